// Round 9
// baseline (525.094 us; speedup 1.0000x reference)
//
#include <hip/hip_runtime.h>
#include <hip/hip_bf16.h>

// Problem dims (fixed by reference): D=512, B=32, S_c=256, S_q(T)=32
#define DIMD 512
#define NB   32
#define NS   256
#define NT   32
// LDS strides chosen for bank-conflict freedom (dword-stride ≡ 1/2 mod 32)
#define SA_STR  66    // ctxdm slice rows (bf16): 132B = 33 dw ≡ 1
#define SCT_STR 258   // ctxT slice rows (bf16): 516B = 129 dw ≡ 1
#define SR_STR  132   // r chunks (fp32): 132 dw ≡ 4 -> q-groups on distinct banks

typedef __bf16 bf16x8 __attribute__((ext_vector_type(8)));
typedef float  f32x4  __attribute__((ext_vector_type(4)));

__device__ __forceinline__ float tanh_fast(float x) {
    float e = __expf(2.f * x);
    return 1.f - 2.f / (e + 1.f);
}

// async global->LDS, 16B per lane; lds dest = wave-uniform base + lane*16
__device__ __forceinline__ void gl_lds16(const __bf16* g, __bf16* l) {
    __builtin_amdgcn_global_load_lds((const __attribute__((address_space(1))) void*)g,
                                     (__attribute__((address_space(3))) void*)l, 16, 0, 0);
}

// ---------------- prep kernels ----------------

// blocks 0..8191: acat rows; 8192..10239: q fp32->bf16; 10240..12287: wcat_nt
__global__ void k_prep(const float* __restrict__ ctxin, const float* __restrict__ img,
                       const float* __restrict__ qin, const float* __restrict__ Wfc1,
                       const float* __restrict__ Wfc2,
                       __bf16* __restrict__ acat, __bf16* __restrict__ qp,
                       __bf16* __restrict__ wcat_nt) {
    int row = blockIdx.x;
    if (row < 8192) {
        int b = row >> 8, s = row & 255;
        const float* c  = ctxin + ((size_t)s * NB + b) * DIMD;
        const float* im = img   + ((size_t)s * NB + b) * DIMD;
        __bf16* o = acat + (size_t)row * 1024;
        for (int d = threadIdx.x; d < DIMD; d += 256) {
            o[d]       = (__bf16)c[d];
            o[512 + d] = (__bf16)im[d];
        }
    } else if (row < 10240) {
        int idx = (row - 8192) * 256 + threadIdx.x;   // 2048*256 = NT*NB*DIMD
        qp[idx] = (__bf16)qin[idx];
    } else {
        int idx = (row - 10240) * 256 + threadIdx.x;  // 2048*256 = 2*512*512
        wcat_nt[idx] = (__bf16)(idx < 262144 ? Wfc1[idx] : Wfc2[idx - 262144]);
    }
}

// fused transpose of six 512x512 weight matrices (fp32 -> bf16), z selects.
// z=0/1 write btc rows 0..511 (wcatT halves); z=2..5 -> wdmT/wqmT/wrmT/wrrT
__global__ void k_transpose_w6(const float* __restrict__ s0, const float* __restrict__ s1,
                               const float* __restrict__ s2, const float* __restrict__ s3,
                               const float* __restrict__ s4_, const float* __restrict__ s5,
                               __bf16* __restrict__ d01, __bf16* __restrict__ d2,
                               __bf16* __restrict__ d3, __bf16* __restrict__ d4,
                               __bf16* __restrict__ d5) {
    __shared__ float tile[32][33];
    int z = blockIdx.z;
    const float* src = (z == 0) ? s0 : (z == 1) ? s1 : (z == 2) ? s2
                     : (z == 3) ? s3 : (z == 4) ? s4_ : s5;
    __bf16* dst; int stride, off;
    if (z < 2) { dst = d01; stride = 1024; off = z * 512; }
    else {
        dst = (z == 2) ? d2 : (z == 3) ? d3 : (z == 4) ? d4 : d5;
        stride = 512; off = 0;
    }
    int c0 = blockIdx.x * 32, r0 = blockIdx.y * 32;
    int x = threadIdx.x, y = threadIdx.y;   // 32 x 8
#pragma unroll
    for (int k = 0; k < 32; k += 8)
        tile[y + k][x] = src[(size_t)(r0 + y + k) * DIMD + c0 + x];
    __syncthreads();
#pragma unroll
    for (int k = 0; k < 32; k += 8)
        dst[(size_t)(c0 + y + k) * stride + off + r0 + x] = (__bf16)tile[x][y + k];
}

// bias_big[0..511] = bfc1+bfc2 ; bias_big[512+o] = (bfc1+bfc2)@Wdm[:,o] + bdm[o]
__global__ void k_bias(const float* __restrict__ bfc1, const float* __restrict__ bfc2,
                       const float* __restrict__ Wdm, const float* __restrict__ bdm,
                       float* __restrict__ bias_big) {
    int o = blockIdx.x * 256 + threadIdx.x;   // grid 4 x 256
    if (o < 512) { bias_big[o] = bfc1[o] + bfc2[o]; return; }
    int od = o - 512;
    float acc = bdm[od];
    for (int d = 0; d < 512; d++)
        acc += (bfc1[d] + bfc2[d]) * Wdm[(size_t)d * 512 + od];
    bias_big[o] = acc;
}

// post-gemm transposes, fused: z<32 -> ctxT per-batch transpose (y<8 active);
// z==32/33 -> W_rg/W_qg fp32->bf16 transpose.  ctxbig row stride 1024, cols 0..511 = ctx
__global__ void k_post_t(const __bf16* __restrict__ ctxbig, __bf16* __restrict__ ctxT,
                         const float* __restrict__ Wrg, const float* __restrict__ Wqg,
                         __bf16* __restrict__ wrgT, __bf16* __restrict__ wqgT) {
    int z = blockIdx.z;
    int x = threadIdx.x, y = threadIdx.y;   // 32 x 8
    if (z < 32) {
        if (blockIdx.y >= 8) return;
        __shared__ __bf16 tile[32][33];
        int c0 = blockIdx.x * 32, s0 = blockIdx.y * 32;
        const __bf16* S = ctxbig + (size_t)z * NS * 1024;
        __bf16* D = ctxT + (size_t)z * DIMD * NS;
#pragma unroll
        for (int k = 0; k < 32; k += 8)
            tile[y + k][x] = S[(size_t)(s0 + y + k) * 1024 + c0 + x];
        __syncthreads();
#pragma unroll
        for (int k = 0; k < 32; k += 8)
            D[(size_t)(c0 + y + k) * NS + s0 + x] = tile[x][y + k];
    } else {
        __shared__ float tf[32][33];
        const float* src = (z == 32) ? Wrg : Wqg;
        __bf16* dst = (z == 32) ? wrgT : wqgT;
        int c0 = blockIdx.x * 32, r0 = blockIdx.y * 32;
#pragma unroll
        for (int k = 0; k < 32; k += 8)
            tf[y + k][x] = src[(size_t)(r0 + y + k) * DIMD + c0 + x];
        __syncthreads();
#pragma unroll
        for (int k = 0; k < 32; k += 8)
            dst[(size_t)(c0 + y + k) * DIMD + r0 + x] = (__bf16)tf[x][y + k];
    }
}

// ---------------- LDS-staged bf16 MFMA GEMM, 64x64 tile ----------------
__global__ void k_gemm64(const __bf16* __restrict__ A, const __bf16* __restrict__ BT,
                         const float* __restrict__ bias1, const float* __restrict__ bias2,
                         void* __restrict__ out, int M, int N, int K, int out_f32) {
    __shared__ __bf16 As[64 * 64];
    __shared__ __bf16 Bs[64 * 64];
    int tid = threadIdx.x, wave = tid >> 6, lane = tid & 63;
    int wm = wave >> 1, wn = wave & 1;
    int m0 = blockIdx.x * 64, n0 = blockIdx.y * 64;
    int lr = lane & 15, lq = lane >> 4;

    f32x4 acc[2][2];
#pragma unroll
    for (int i = 0; i < 2; i++)
#pragma unroll
        for (int j = 0; j < 2; j++) acc[i][j] = (f32x4){0.f, 0.f, 0.f, 0.f};

    int g0 = (wave * 2 + 0) * 64 + lane;
    int g1 = (wave * 2 + 1) * 64 + lane;
    int r0_ = g0 >> 3, c0_ = g0 & 7;
    int r1_ = g1 >> 3, c1_ = g1 & 7;
    __bf16* la0 = As + (wave * 2 + 0) * 512;
    __bf16* la1 = As + (wave * 2 + 1) * 512;
    __bf16* lb0 = Bs + (wave * 2 + 0) * 512;
    __bf16* lb1 = Bs + (wave * 2 + 1) * 512;

    for (int kk = 0; kk < K; kk += 64) {
        gl_lds16(A  + (size_t)(m0 + r0_) * K + kk + c0_ * 8, la0);
        gl_lds16(A  + (size_t)(m0 + r1_) * K + kk + c1_ * 8, la1);
        gl_lds16(BT + (size_t)(n0 + r0_) * K + kk + c0_ * 8, lb0);
        gl_lds16(BT + (size_t)(n0 + r1_) * K + kk + c1_ * 8, lb1);
        __syncthreads();
#pragma unroll
        for (int k2 = 0; k2 < 64; k2 += 32) {
            bf16x8 af[2], bfv[2];
#pragma unroll
            for (int i = 0; i < 2; i++)
                af[i] = *(const bf16x8*)(As + (wm * 32 + i * 16 + lr) * 64 + k2 + lq * 8);
#pragma unroll
            for (int j = 0; j < 2; j++)
                bfv[j] = *(const bf16x8*)(Bs + (wn * 32 + j * 16 + lr) * 64 + k2 + lq * 8);
#pragma unroll
            for (int i = 0; i < 2; i++)
#pragma unroll
                for (int j = 0; j < 2; j++)
                    acc[i][j] = __builtin_amdgcn_mfma_f32_16x16x32_bf16(af[i], bfv[j], acc[i][j], 0, 0, 0);
        }
        __syncthreads();
    }

#pragma unroll
    for (int i = 0; i < 2; i++)
#pragma unroll
        for (int j = 0; j < 2; j++) {
            int col = n0 + wn * 32 + j * 16 + lr;
            float bs = (bias1 ? bias1[col] : 0.f) + (bias2 ? bias2[col] : 0.f);
#pragma unroll
            for (int r = 0; r < 4; r++) {
                int row = m0 + wm * 32 + i * 16 + lq * 4 + r;
                float v = acc[i][j][r] + bs;
                if (out_f32) ((float*)out)[(size_t)row * N + col] = v;
                else         ((__bf16*)out)[(size_t)row * N + col] = (__bf16)v;
            }
        }
}

// ---------------- scan: 8 blocks/batch, per-block flag sync, on-chip state ----------------

// Flag barrier: per-block monotone flag stores (no RMW serialization); lanes 0-7
// of wave 0 poll all 8 flags in parallel. No acquire/release fences (they emit
// buffer_inv/wbl2 -> 23us/barrier, round 3); RELAXED uncached atomics + per-wave
// vmcnt drain at __syncthreads give ordering (proven rounds 5-7).
__device__ __forceinline__ void bflag(unsigned* fb, int j, unsigned tgt) {
    __syncthreads();                       // all waves' stores drained (vmcnt 0)
    if (threadIdx.x == 0) {
        __atomic_signal_fence(__ATOMIC_SEQ_CST);
        __builtin_amdgcn_s_waitcnt(0x0F70);   // vmcnt(0) belt-and-suspenders
        __atomic_signal_fence(__ATOMIC_SEQ_CST);
        __hip_atomic_store(fb + j * 16, tgt, __ATOMIC_RELAXED, __HIP_MEMORY_SCOPE_AGENT);
    }
    if (threadIdx.x < 8) {
        while (__hip_atomic_load(fb + threadIdx.x * 16, __ATOMIC_RELAXED,
                                 __HIP_MEMORY_SCOPE_AGENT) < tgt)
            __builtin_amdgcn_s_sleep(1);
    }
    __syncthreads();
}

// grid 256 = 32 batches x 8 e-slices; block 512 threads (8 waves), 1 block/CU.
// XCD-affinity swizzle: b = bid&31, j = bid>>5 -> a batch's 8 blocks share
// bid%8 (heuristic round-robin -> same XCD; correctness-neutral).
__global__ __launch_bounds__(512, 2) void k_scan(
    const __bf16* __restrict__ ctxbig, // [b*256+s][1024]: cols 0-511 ctx, 512-1023 ctxdm
    const __bf16* __restrict__ ctxT,   // [b][c][s]
    const __bf16* __restrict__ wrmT,   // [c][d]
    const __bf16* __restrict__ wrrT,   // [c][d]
    const float* __restrict__ qmf,     // [t*32+b][512]
    const float* __restrict__ wms, const float* __restrict__ brm,
    const float* __restrict__ brr,
    float* partials,                   // [b][8][256]
    float* rpub,                       // [b][512]
    unsigned* flags,                   // [256][16], zeroed
    float* __restrict__ rbuf) {
    int bid = blockIdx.x;
    int b = bid & 31, j = bid >> 5;        // XCD-affinity mapping
    int tid = threadIdx.x, wave = tid >> 6, lane = tid & 63;
    int g = lane >> 3, i = lane & 7;       // s-subgroup, e-chunk

    __shared__ __bf16 sA[256 * SA_STR];    // 33.8 KB (ctxdm slice)
    __shared__ __bf16 sCT[64 * SCT_STR];   // 33.0 KB (ctxT slice)
    __shared__ float  sQ[NT * 64];         //  8 KB
    __shared__ float  spart[NS];
    __shared__ float  sp[NS];
    __shared__ float  sq[512];
    __shared__ float  s4[4];
    __shared__ float  sps[8 * 68];         // B1 per-wave partials (stride 68)
    __shared__ float  srm[64], sh[64];
    __shared__ float  sr4[4 * SR_STR];     // r in 4 padded chunks
    __shared__ float  smv[512];

    unsigned* fb = flags + b * 8 * 16;

    // ---- one-time staging ----
    for (int c = tid; c < 2048; c += 512) {            // sA: 256 rows x 64 e (ctxdm = cols 512+)
        int row = c >> 3, c8 = c & 7;
        *(bf16x8*)(sA + row * SA_STR + c8 * 8) =
            *(const bf16x8*)(ctxbig + ((size_t)(b * NS + row)) * 1024 + 512 + j * 64 + c8 * 8);
    }
    for (int c = tid; c < 2048; c += 512) {            // sCT: 64 cols x 256 s
        int col = c >> 5, s8 = c & 31;
        *(bf16x8*)(sCT + col * SCT_STR + s8 * 8) =
            *(const bf16x8*)(ctxT + ((size_t)(b * DIMD) + j * 64 + col) * NS + s8 * 8);
    }
    for (int c = tid; c < NT * 64; c += 512) {         // sQ
        int tt = c >> 6, e = c & 63;
        sQ[c] = qmf[((size_t)tt * NB + b) * DIMD + j * 64 + e];
    }
    // weight slice -> registers: thread (m,cl,q) owns d in [q*128,(q+1)*128)
    int m = tid >> 8, cl = (tid >> 2) & 63, q = tid & 3;
    const __bf16* wp = (m ? wrrT : wrmT) + ((size_t)(j * 64 + cl)) * DIMD + q * 128;
    bf16x8 wreg[16];
#pragma unroll
    for (int u = 0; u < 16; u++) wreg[u] = *(const bf16x8*)(wp + u * 8);

    float wm[8];
#pragma unroll
    for (int u = 0; u < 8; u++) wm[u] = wms[j * 64 + i * 8 + u];
    if (tid < 64) {
        srm[tid] = brm[j * 64 + tid];            // rm_0 slice (r0 = 0)
        sh[tid]  = tanh_fast(brr[j * 64 + tid]); // h_0 slice
    }
    __syncthreads();

    unsigned ph = 1;
    for (int t = 0; t < NT; t++) {
        // ---- phase A: partial logits over own e-slice (all LDS) ----
        float rq[8];
#pragma unroll
        for (int u = 0; u < 8; u++) rq[u] = srm[i * 8 + u] + sQ[t * 64 + i * 8 + u];
#pragma unroll
        for (int k = 0; k < 4; k++) {
            int s = wave * 32 + k * 8 + g;
            bf16x8 cv = *(const bf16x8*)(sA + s * SA_STR + i * 8);
            float a = 0.f;
#pragma unroll
            for (int u = 0; u < 8; u++)
                a += tanh_fast((float)cv[u] + rq[u]) * wm[u];
            a += __shfl_xor(a, 1); a += __shfl_xor(a, 2); a += __shfl_xor(a, 4);
            if (i == 0) spart[s] = a;
        }
        __syncthreads();
        if (tid < NS)
            __hip_atomic_store(&partials[(b * 8 + j) * NS + tid], spart[tid],
                               __ATOMIC_RELAXED, __HIP_MEMORY_SCOPE_AGENT);
        bflag(fb, j, ph); ph++;

        // ---- phase B1: gather partials, softmax, weighted ctx sum -> r-slice ----
        {
            int s = tid >> 1, jh = (tid & 1) * 4;
            float a = 0.f;
#pragma unroll
            for (int u = 0; u < 4; u++)
                a += __hip_atomic_load(&partials[(b * 8 + jh + u) * NS + s],
                                       __ATOMIC_RELAXED, __HIP_MEMORY_SCOPE_AGENT);
            sq[tid] = a;
        }
        __syncthreads();
        float ev = 0.f;
        if (tid < NS) { ev = __expf(sq[2 * tid] + sq[2 * tid + 1]); sp[tid] = ev; }
#pragma unroll
        for (int off = 32; off; off >>= 1) ev += __shfl_xor(ev, off);
        if (tid < NS && lane == 0) s4[wave] = ev;
        __syncthreads();
        float inv = 1.f / (s4[0] + s4[1] + s4[2] + s4[3]);
        {
            // wave = s-chunk, lane = col: per-lane linear LDS streams (2-way max)
            const __bf16* cp = sCT + lane * SCT_STR + wave * 32;
            const float* pp = sp + wave * 32;
            float a = 0.f;
#pragma unroll
            for (int k = 0; k < 32; k += 8) {
                bf16x8 v = *(const bf16x8*)(cp + k);
#pragma unroll
                for (int u = 0; u < 8; u++) a = fmaf(pp[k + u], (float)v[u], a);
            }
            sps[wave * 68 + lane] = a;
        }
        __syncthreads();
        if (tid < 64) {
            float a = 0.f;
#pragma unroll
            for (int w2 = 0; w2 < 8; w2++) a += sps[w2 * 68 + tid];
            float rv = a * inv + sh[tid];
            if (t == NT - 1) rbuf[b * DIMD + j * 64 + tid] = rv;   // final r
            else
                __hip_atomic_store(&rpub[b * DIMD + j * 64 + tid], rv,
                                   __ATOMIC_RELAXED, __HIP_MEMORY_SCOPE_AGENT);
        }
        if (t == NT - 1) break;            // no consumers after last step
        bflag(fb, j, ph); ph++;

        // ---- phase B2: gather r, register-weight matvec -> rm/h (block-local) ----
        sr4[(tid >> 7) * SR_STR + (tid & 127)] =
            __hip_atomic_load(&rpub[b * DIMD + tid], __ATOMIC_RELAXED, __HIP_MEMORY_SCOPE_AGENT);
        __syncthreads();
        {
            const float* sv = sr4 + q * SR_STR;   // q-groups land on distinct banks
            float a0 = 0.f, a1 = 0.f;
#pragma unroll
            for (int u = 0; u < 16; u += 2) {
                bf16x8 w0 = wreg[u], w1 = wreg[u + 1];
#pragma unroll
                for (int e = 0; e < 8; e++) {
                    a0 = fmaf(sv[u * 8 + e],     (float)w0[e], a0);
                    a1 = fmaf(sv[u * 8 + 8 + e], (float)w1[e], a1);
                }
            }
            smv[tid] = a0 + a1;
        }
        __syncthreads();
        if (tid < 128) {
            int m2 = tid >> 6, cl3 = tid & 63;
            float a = smv[m2 * 256 + cl3 * 4] + smv[m2 * 256 + cl3 * 4 + 1]
                    + smv[m2 * 256 + cl3 * 4 + 2] + smv[m2 * 256 + cl3 * 4 + 3];
            int col = j * 64 + cl3;
            if (m2 == 0) srm[cl3] = a + brm[col];
            else         sh[cl3]  = tanh_fast(a + brr[col]);
        }
        __syncthreads();
    }
}

// g = r@W_rg + b_rg + qh@W_qg + b_qg  (bf16 [col][d] weights, contiguous reads)
__global__ void k_final2(const float* __restrict__ r, const float* __restrict__ qh,
                         const __bf16* __restrict__ wrgT, const __bf16* __restrict__ wqgT,
                         const float* __restrict__ brg, const float* __restrict__ bqg,
                         float* __restrict__ out) {
    int clx = threadIdx.x & 7, b = threadIdx.x >> 3;
    int col = blockIdx.x * 8 + clx;
    const __bf16* w1 = wrgT + (size_t)col * DIMD;
    const __bf16* w2 = wqgT + (size_t)col * DIMD;
    const float* rp = r + (size_t)b * DIMD;
    const float* qp = qh + (size_t)b * DIMD;
    float acc = brg[col] + bqg[col];
#pragma unroll 4
    for (int d = 0; d < DIMD; d += 8) {
        bf16x8 a = *(const bf16x8*)(w1 + d);
        bf16x8 c = *(const bf16x8*)(w2 + d);
#pragma unroll
        for (int u = 0; u < 8; u++)
            acc += rp[d + u] * (float)a[u] + qp[d + u] * (float)c[u];
    }
    out[b * DIMD + col] = acc;
}

// ---------------- host ----------------

extern "C" void kernel_launch(void* const* d_in, const int* in_sizes, int n_in,
                              void* d_out, int out_size, void* d_ws, size_t ws_size,
                              hipStream_t stream) {
    const float* ctx_in = (const float*)d_in[0];
    const float* q_in   = (const float*)d_in[1];
    const float* qh     = (const float*)d_in[2];
    const float* img    = (const float*)d_in[3];
    const float* W_fc1  = (const float*)d_in[4];
    const float* b_fc1  = (const float*)d_in[5];
    const float* W_fc2  = (const float*)d_in[6];
    const float* b_fc2  = (const float*)d_in[7];
    const float* W_dm   = (const float*)d_in[8];
    const float* b_dm   = (const float*)d_in[9];
    const float* W_rm   = (const float*)d_in[10];
    const float* b_rm   = (const float*)d_in[11];
    const float* W_qm   = (const float*)d_in[12];
    const float* b_qm   = (const float*)d_in[13];
    const float* W_rr   = (const float*)d_in[14];
    const float* b_rr   = (const float*)d_in[15];
    const float* W_rg   = (const float*)d_in[16];
    const float* b_rg   = (const float*)d_in[17];
    const float* W_qg   = (const float*)d_in[18];
    const float* b_qg   = (const float*)d_in[19];
    const float* W_ms   = (const float*)d_in[20];
    // d_in[21] = b_ms: unused (softmax shift-invariant)

    // workspace layout. RULE (round-8 bug): the x-region below aliases acat and
    // may only be WRITTEN after the big GEMM consumed acat. biasb is written
    // BEFORE that -> it lives in the main (non-aliased) chain.
    char* w = (char*)d_ws;
    __bf16* acat   = (__bf16*)w;  w += (size_t)8192 * 1024 * 2;   // 16.78 MB, dead after big GEMM
    __bf16* qp     = (__bf16*)w;  w += (size_t)1024 * 512 * 2;    //  1.05 MB
    __bf16* btc    = (__bf16*)w;  w += (size_t)1024 * 1024 * 2;   //  2.10 MB combined BT
    __bf16* wdmT   = (__bf16*)w;  w += (size_t)512 * 512 * 2;
    __bf16* wqmT   = (__bf16*)w;  w += (size_t)512 * 512 * 2;
    __bf16* wrmT2  = (__bf16*)w;  w += (size_t)512 * 512 * 2;
    __bf16* wrrT2  = (__bf16*)w;  w += (size_t)512 * 512 * 2;
    float*  biasb  = (float*)w;   w += (size_t)1024 * 4;          //  4 KB (NOT aliased!)
    __bf16* ctxbig = (__bf16*)w;  w += (size_t)8192 * 1024 * 2;   // 16.78 MB [ctx|ctxdm]
    // wcat_nt aliases ctxbig head: consumed by small GEMM before big GEMM writes ctxbig
    __bf16* wcat_nt = ctxbig;                                     // [1024][512] bf16
    // sub-allocate dead acat region (written only after big GEMM consumed it)
    char* x = (char*)acat;
    __bf16*   ctxT  = (__bf16*)x;    x += (size_t)NB * DIMD * NS * 2;  // 8.39 MB
    float*    qmf   = (float*)x;     x += (size_t)1024 * 512 * 4;      // 2.10 MB
    __bf16*   wrgT  = (__bf16*)x;    x += (size_t)512 * 512 * 2;
    __bf16*   wqgT  = (__bf16*)x;    x += (size_t)512 * 512 * 2;
    float*    rpub  = (float*)x;     x += (size_t)NB * DIMD * 4;
    float*    parts = (float*)x;     x += (size_t)NB * 8 * NS * 4;
    float*    rbuf  = (float*)x;     x += (size_t)NB * DIMD * 4;
    unsigned* flags = (unsigned*)x;  x += (size_t)256 * 16 * 4;

    // prep: acat + qp + wcat_nt (plain bf16 cast of [Wfc1;Wfc2])
    k_prep<<<12288, 256, 0, stream>>>(ctx_in, img, q_in, W_fc1, W_fc2, acat, qp, wcat_nt);
    // 6 transposes: wcatT -> btc rows 0..511, + wdmT/wqmT/wrmT/wrrT
    k_transpose_w6<<<dim3(16, 16, 6), dim3(32, 8), 0, stream>>>(
        W_fc1, W_fc2, W_dm, W_qm, W_rm, W_rr, btc, wdmT, wqmT, wrmT2, wrrT2);
    // combined bias: [bfc1+bfc2 | (bfc1+bfc2)@Wdm + bdm]  (biasb in main chain)
    k_bias<<<4, 256, 0, stream>>>(b_fc1, b_fc2, W_dm, b_dm, biasb);
    // small GEMM: btc rows 512..1023 = (W_cat@W_dm)^T
    k_gemm64<<<dim3(8, 16), 256, 0, stream>>>(wdmT, wcat_nt, nullptr, nullptr,
                                              btc + (size_t)512 * 1024, 512, 1024, 512, 0);
    // big fused GEMM: ctxbig[8192][1024] = acat @ [W_cat | W_cat@W_dm] + biasb
    k_gemm64<<<dim3(128, 16), 256, 0, stream>>>(acat, btc, biasb, nullptr,
                                                ctxbig, 8192, 1024, 1024, 0);
    // acat dead: ctxT + W_rg/W_qg transposes into its place
    k_post_t<<<dim3(16, 16, 34), dim3(32, 8), 0, stream>>>(ctxbig, ctxT, W_rg, W_qg, wrgT, wqgT);
    // qm GEMM
    k_gemm64<<<dim3(16, 8), 256, 0, stream>>>(qp, wqmT, b_qm, nullptr, qmf, 1024, 512, 512, 1);

    // zero flags (ws is 0xAA-poisoned before every launch)
    hipMemsetAsync(flags, 0, (size_t)256 * 16 * 4, stream);

    // full-machine scan: 256 blocks (8 per batch) x 512 threads
    k_scan<<<256, 512, 0, stream>>>(ctxbig, ctxT, wrmT2, wrrT2, qmf, W_ms,
                                    b_rm, b_rr, parts, rpub, flags, rbuf);

    k_final2<<<64, 256, 0, stream>>>(rbuf, qh, wrgT, wqgT, b_rg, b_qg, (float*)d_out);
}

// Round 10
// 467.520 us; speedup vs baseline: 1.1231x; 1.1231x over previous
//
#include <hip/hip_runtime.h>
#include <hip/hip_bf16.h>

// Problem dims (fixed by reference): D=512, B=32, S_c=256, S_q(T)=32
#define DIMD 512
#define NB   32
#define NS   256
#define NT   32
// LDS strides chosen for bank-conflict freedom (dword-stride ≡ 1/2 mod 32)
#define SA_STR  66    // ctxdm slice rows (bf16): 132B = 33 dw ≡ 1
#define SCT_STR 258   // ctxT slice rows (bf16): 516B = 129 dw ≡ 1
#define SR_STR  132   // r chunks (fp32): 132 dw ≡ 4 -> q-groups on distinct banks

typedef __bf16 bf16x8 __attribute__((ext_vector_type(8)));
typedef float  f32x4  __attribute__((ext_vector_type(4)));
typedef unsigned long long u64;

__device__ __forceinline__ float tanh_fast(float x) {
    float e = __expf(2.f * x);
    return 1.f - 2.f / (e + 1.f);
}

// async global->LDS, 16B per lane; lds dest = wave-uniform base + lane*16
__device__ __forceinline__ void gl_lds16(const __bf16* g, __bf16* l) {
    __builtin_amdgcn_global_load_lds((const __attribute__((address_space(1))) void*)g,
                                     (__attribute__((address_space(3))) void*)l, 16, 0, 0);
}

// ---- tagged-data sync (round 10): {value,tag} in one 64-bit relaxed atomic.
// Tag+value arrive atomically -> no flags, no fences, no vmcnt drains. Causality
// via data dependence (consumer's published value depends on polled loads).
// Tags 1..NT never collide with the 0xAAAAAAAA workspace poison.
__device__ __forceinline__ void pub64(u64* p, float v, unsigned tag) {
    u64 pk = ((u64)__float_as_uint(v) << 32) | (u64)tag;
    __hip_atomic_store(p, pk, __ATOMIC_RELAXED, __HIP_MEMORY_SCOPE_AGENT);
}
__device__ __forceinline__ float poll64(const u64* p, unsigned tag) {
    u64 v = __hip_atomic_load(p, __ATOMIC_RELAXED, __HIP_MEMORY_SCOPE_AGENT);
    while ((unsigned)v != tag) {
        __builtin_amdgcn_s_sleep(1);
        v = __hip_atomic_load(p, __ATOMIC_RELAXED, __HIP_MEMORY_SCOPE_AGENT);
    }
    return __uint_as_float((unsigned)(v >> 32));
}

// ---------------- fused prep: acat + q cast + six weight transposes ----------------
// blocks 0..8191: acat rows; 8192..10239: q fp32->bf16; 10240..11775: transposes
__global__ void k_prep_all(const float* __restrict__ ctxin, const float* __restrict__ img,
                           const float* __restrict__ qin,
                           const float* __restrict__ Wfc1, const float* __restrict__ Wfc2,
                           const float* __restrict__ Wdm, const float* __restrict__ Wqm,
                           const float* __restrict__ Wrm, const float* __restrict__ Wrr,
                           __bf16* __restrict__ acat, __bf16* __restrict__ qp,
                           __bf16* __restrict__ wcatT, __bf16* __restrict__ wdmT,
                           __bf16* __restrict__ wqmT, __bf16* __restrict__ wrmT,
                           __bf16* __restrict__ wrrT) {
    int row = blockIdx.x;
    if (row < 8192) {
        int b = row >> 8, s = row & 255;
        const float* c  = ctxin + ((size_t)s * NB + b) * DIMD;
        const float* im = img   + ((size_t)s * NB + b) * DIMD;
        __bf16* o = acat + (size_t)row * 1024;
        for (int d = threadIdx.x; d < DIMD; d += 256) {
            o[d]       = (__bf16)c[d];
            o[512 + d] = (__bf16)im[d];
        }
    } else if (row < 10240) {
        int idx = (row - 8192) * 256 + threadIdx.x;   // 2048*256 = NT*NB*DIMD
        qp[idx] = (__bf16)qin[idx];
    } else {
        __shared__ float tile[32][33];
        int zz = (row - 10240) >> 8;       // matrix id 0..5
        int idx = (row - 10240) & 255;
        int bx = idx & 15, by = idx >> 4;
        int x = threadIdx.x & 31, y = threadIdx.x >> 5;   // 32 x 8
        const float* src = (zz == 0) ? Wfc1 : (zz == 1) ? Wfc2 : (zz == 2) ? Wdm
                         : (zz == 3) ? Wqm : (zz == 4) ? Wrm : Wrr;
        __bf16* dst; int stride, off;
        if (zz < 2) { dst = wcatT; stride = 1024; off = zz * 512; }
        else {
            dst = (zz == 2) ? wdmT : (zz == 3) ? wqmT : (zz == 4) ? wrmT : wrrT;
            stride = 512; off = 0;
        }
        int c0 = bx * 32, r0 = by * 32;
#pragma unroll
        for (int k = 0; k < 32; k += 8)
            tile[y + k][x] = src[(size_t)(r0 + y + k) * DIMD + c0 + x];
        __syncthreads();
#pragma unroll
        for (int k = 0; k < 32; k += 8)
            dst[(size_t)(c0 + y + k) * stride + off + r0 + x] = (__bf16)tile[x][y + k];
    }
}

// post-g1 transposes, fused: z<32 -> ctxT per-batch transpose (y<8 active);
// z==32/33 -> W_rg/W_qg fp32->bf16 transpose.  ctxb rows [b*256+s][512]
__global__ void k_post_t(const __bf16* __restrict__ ctxb, __bf16* __restrict__ ctxT,
                         const float* __restrict__ Wrg, const float* __restrict__ Wqg,
                         __bf16* __restrict__ wrgT, __bf16* __restrict__ wqgT) {
    int z = blockIdx.z;
    int x = threadIdx.x, y = threadIdx.y;   // 32 x 8
    if (z < 32) {
        if (blockIdx.y >= 8) return;
        __shared__ __bf16 tile[32][33];
        int c0 = blockIdx.x * 32, s0 = blockIdx.y * 32;
        const __bf16* S = ctxb + (size_t)z * NS * DIMD;
        __bf16* D = ctxT + (size_t)z * DIMD * NS;
#pragma unroll
        for (int k = 0; k < 32; k += 8)
            tile[y + k][x] = S[(size_t)(s0 + y + k) * DIMD + c0 + x];
        __syncthreads();
#pragma unroll
        for (int k = 0; k < 32; k += 8)
            D[(size_t)(c0 + y + k) * NS + s0 + x] = tile[x][y + k];
    } else {
        __shared__ float tf[32][33];
        const float* src = (z == 32) ? Wrg : Wqg;
        __bf16* dst = (z == 32) ? wrgT : wqgT;
        int c0 = blockIdx.x * 32, r0 = blockIdx.y * 32;
#pragma unroll
        for (int k = 0; k < 32; k += 8)
            tf[y + k][x] = src[(size_t)(r0 + y + k) * DIMD + c0 + x];
        __syncthreads();
#pragma unroll
        for (int k = 0; k < 32; k += 8)
            dst[(size_t)(c0 + y + k) * DIMD + r0 + x] = (__bf16)tf[x][y + k];
    }
}

// ---------------- LDS-staged bf16 MFMA GEMM, 64x64 tile ----------------
__global__ void k_gemm64(const __bf16* __restrict__ A, const __bf16* __restrict__ BT,
                         const float* __restrict__ bias1, const float* __restrict__ bias2,
                         void* __restrict__ out, int M, int N, int K, int out_f32) {
    __shared__ __bf16 As[64 * 64];
    __shared__ __bf16 Bs[64 * 64];
    int tid = threadIdx.x, wave = tid >> 6, lane = tid & 63;
    int wm = wave >> 1, wn = wave & 1;
    int m0 = blockIdx.x * 64, n0 = blockIdx.y * 64;
    int lr = lane & 15, lq = lane >> 4;

    f32x4 acc[2][2];
#pragma unroll
    for (int i = 0; i < 2; i++)
#pragma unroll
        for (int j = 0; j < 2; j++) acc[i][j] = (f32x4){0.f, 0.f, 0.f, 0.f};

    int g0 = (wave * 2 + 0) * 64 + lane;
    int g1 = (wave * 2 + 1) * 64 + lane;
    int r0_ = g0 >> 3, c0_ = g0 & 7;
    int r1_ = g1 >> 3, c1_ = g1 & 7;
    __bf16* la0 = As + (wave * 2 + 0) * 512;
    __bf16* la1 = As + (wave * 2 + 1) * 512;
    __bf16* lb0 = Bs + (wave * 2 + 0) * 512;
    __bf16* lb1 = Bs + (wave * 2 + 1) * 512;

    for (int kk = 0; kk < K; kk += 64) {
        gl_lds16(A  + (size_t)(m0 + r0_) * K + kk + c0_ * 8, la0);
        gl_lds16(A  + (size_t)(m0 + r1_) * K + kk + c1_ * 8, la1);
        gl_lds16(BT + (size_t)(n0 + r0_) * K + kk + c0_ * 8, lb0);
        gl_lds16(BT + (size_t)(n0 + r1_) * K + kk + c1_ * 8, lb1);
        __syncthreads();
#pragma unroll
        for (int k2 = 0; k2 < 64; k2 += 32) {
            bf16x8 af[2], bfv[2];
#pragma unroll
            for (int i = 0; i < 2; i++)
                af[i] = *(const bf16x8*)(As + (wm * 32 + i * 16 + lr) * 64 + k2 + lq * 8);
#pragma unroll
            for (int j = 0; j < 2; j++)
                bfv[j] = *(const bf16x8*)(Bs + (wn * 32 + j * 16 + lr) * 64 + k2 + lq * 8);
#pragma unroll
            for (int i = 0; i < 2; i++)
#pragma unroll
                for (int j = 0; j < 2; j++)
                    acc[i][j] = __builtin_amdgcn_mfma_f32_16x16x32_bf16(af[i], bfv[j], acc[i][j], 0, 0, 0);
        }
        __syncthreads();
    }

#pragma unroll
    for (int i = 0; i < 2; i++)
#pragma unroll
        for (int j = 0; j < 2; j++) {
            int col = n0 + wn * 32 + j * 16 + lr;
            float bs = (bias1 ? bias1[col] : 0.f) + (bias2 ? bias2[col] : 0.f);
#pragma unroll
            for (int r = 0; r < 4; r++) {
                int row = m0 + wm * 32 + i * 16 + lq * 4 + r;
                float v = acc[i][j][r] + bs;
                if (out_f32) ((float*)out)[(size_t)row * N + col] = v;
                else         ((__bf16*)out)[(size_t)row * N + col] = (__bf16)v;
            }
        }
}

// ---------------- scan: 8 blocks/batch, tagged-data sync, on-chip state ----------------
// grid 256 = 32 batches x 8 e-slices; block 512 threads (8 waves), 1 block/CU.
// XCD-affinity: b = bid&31, j = bid>>5 (a batch's 8 blocks share bid%8 -> same
// XCD under round-robin; halved scan FETCH in round 9).
__global__ __launch_bounds__(512, 2) void k_scan(
    const __bf16* __restrict__ ctxdm,  // [b*256+s][512]
    const __bf16* __restrict__ ctxT,   // [b][c][s]
    const __bf16* __restrict__ wrmT,   // [c][d]
    const __bf16* __restrict__ wrrT,   // [c][d]
    const float* __restrict__ qmf,     // [t*32+b][512]
    const float* __restrict__ wms, const float* __restrict__ brm,
    const float* __restrict__ brr,
    u64* parts,                        // [b][8][256] tagged
    u64* rpub,                         // [b][512] tagged
    float* __restrict__ rbuf) {
    int bid = blockIdx.x;
    int b = bid & 31, j = bid >> 5;        // XCD-affinity mapping
    int tid = threadIdx.x, wave = tid >> 6, lane = tid & 63;
    int g = lane >> 3, i = lane & 7;       // s-subgroup, e-chunk

    __shared__ __bf16 sA[256 * SA_STR];    // 33.8 KB (ctxdm slice)
    __shared__ __bf16 sCT[64 * SCT_STR];   // 33.0 KB (ctxT slice)
    __shared__ float  sQ[NT * 64];         //  8 KB
    __shared__ float  spart[NS];
    __shared__ float  sq[512];
    __shared__ float  s4[4];
    __shared__ float  sps[8 * 68];         // B1 per-wave partials (stride 68)
    __shared__ float  srm[64], sh[64];
    __shared__ float  sr4[4 * SR_STR];     // r in 4 padded chunks
    __shared__ float  smv[512];

    // ---- one-time staging ----
    for (int c = tid; c < 2048; c += 512) {            // sA: 256 rows x 64 e
        int row = c >> 3, c8 = c & 7;
        *(bf16x8*)(sA + row * SA_STR + c8 * 8) =
            *(const bf16x8*)(ctxdm + ((size_t)(b * NS + row)) * DIMD + j * 64 + c8 * 8);
    }
    for (int c = tid; c < 2048; c += 512) {            // sCT: 64 cols x 256 s
        int col = c >> 5, s8 = c & 31;
        *(bf16x8*)(sCT + col * SCT_STR + s8 * 8) =
            *(const bf16x8*)(ctxT + ((size_t)(b * DIMD) + j * 64 + col) * NS + s8 * 8);
    }
    for (int c = tid; c < NT * 64; c += 512) {         // sQ
        int tt = c >> 6, e = c & 63;
        sQ[c] = qmf[((size_t)tt * NB + b) * DIMD + j * 64 + e];
    }
    // weight slice -> registers: thread (m,cl,q) owns d in [q*128,(q+1)*128)
    int m = tid >> 8, cl = (tid >> 2) & 63, q = tid & 3;
    const __bf16* wp = (m ? wrrT : wrmT) + ((size_t)(j * 64 + cl)) * DIMD + q * 128;
    bf16x8 wreg[16];
#pragma unroll
    for (int u = 0; u < 16; u++) wreg[u] = *(const bf16x8*)(wp + u * 8);

    float wm[8];
#pragma unroll
    for (int u = 0; u < 8; u++) wm[u] = wms[j * 64 + i * 8 + u];
    if (tid < 64) {
        srm[tid] = brm[j * 64 + tid];            // rm_0 slice (r0 = 0)
        sh[tid]  = tanh_fast(brr[j * 64 + tid]); // h_0 slice
    }
    __syncthreads();

    for (int t = 0; t < NT; t++) {
        unsigned tag = (unsigned)(t + 1);
        // ---- phase A: partial logits over own e-slice (all LDS) ----
        float rq[8];
#pragma unroll
        for (int u = 0; u < 8; u++) rq[u] = srm[i * 8 + u] + sQ[t * 64 + i * 8 + u];
#pragma unroll
        for (int k = 0; k < 4; k++) {
            int s = wave * 32 + k * 8 + g;
            bf16x8 cv = *(const bf16x8*)(sA + s * SA_STR + i * 8);
            float a = 0.f;
#pragma unroll
            for (int u = 0; u < 8; u++)
                a += tanh_fast((float)cv[u] + rq[u]) * wm[u];
            a += __shfl_xor(a, 1); a += __shfl_xor(a, 2); a += __shfl_xor(a, 4);
            if (i == 0) spart[s] = a;
        }
        __syncthreads();
        if (tid < NS)
            pub64(&parts[(b * 8 + j) * NS + tid], spart[tid], tag);

        // ---- phase B1: poll partials, softmax, weighted ctx sum -> r-slice ----
        {
            int s = tid >> 1, jh = (tid & 1) * 4;
            float a = 0.f;
#pragma unroll
            for (int u = 0; u < 4; u++)
                a += poll64(&parts[(b * 8 + jh + u) * NS + s], tag);
            sq[tid] = a;
        }
        __syncthreads();
        float ev = 0.f;
        if (tid < NS) { ev = __expf(sq[2 * tid] + sq[2 * tid + 1]); sq[tid] = ev; }
        else sq[tid] = 0.f;   // unused half
#pragma unroll
        for (int off = 32; off; off >>= 1) ev += __shfl_xor(ev, off);
        if (tid < NS && lane == 0) s4[wave] = ev;
        __syncthreads();
        float inv = 1.f / (s4[0] + s4[1] + s4[2] + s4[3]);
        {
            // wave = s-chunk, lane = col: per-lane linear LDS streams (2-way max)
            const __bf16* cp = sCT + lane * SCT_STR + wave * 32;
            const float* pp = sq + wave * 32;   // exp values live in sq[0..255]
            float a = 0.f;
#pragma unroll
            for (int k = 0; k < 32; k += 8) {
                bf16x8 v = *(const bf16x8*)(cp + k);
#pragma unroll
                for (int u = 0; u < 8; u++) a = fmaf(pp[k + u], (float)v[u], a);
            }
            sps[wave * 68 + lane] = a;
        }
        __syncthreads();
        if (tid < 64) {
            float a = 0.f;
#pragma unroll
            for (int w2 = 0; w2 < 8; w2++) a += sps[w2 * 68 + tid];
            float rv = a * inv + sh[tid];
            if (t == NT - 1) rbuf[b * DIMD + j * 64 + tid] = rv;   // final r
            else             pub64(&rpub[b * DIMD + j * 64 + tid], rv, tag);
        }
        if (t == NT - 1) break;            // no consumers after last step

        // ---- phase B2: poll r, register-weight matvec -> rm/h (block-local) ----
        sr4[(tid >> 7) * SR_STR + (tid & 127)] = poll64(&rpub[b * DIMD + tid], tag);
        __syncthreads();
        {
            const float* sv = sr4 + q * SR_STR;   // q-groups land on distinct banks
            float a0 = 0.f, a1 = 0.f;
#pragma unroll
            for (int u = 0; u < 16; u += 2) {
                bf16x8 w0 = wreg[u], w1 = wreg[u + 1];
#pragma unroll
                for (int e = 0; e < 8; e++) {
                    a0 = fmaf(sv[u * 8 + e],     (float)w0[e], a0);
                    a1 = fmaf(sv[u * 8 + 8 + e], (float)w1[e], a1);
                }
            }
            smv[tid] = a0 + a1;
        }
        __syncthreads();
        if (tid < 128) {
            int m2 = tid >> 6, cl3 = tid & 63;
            float a = smv[m2 * 256 + cl3 * 4] + smv[m2 * 256 + cl3 * 4 + 1]
                    + smv[m2 * 256 + cl3 * 4 + 2] + smv[m2 * 256 + cl3 * 4 + 3];
            int col = j * 64 + cl3;
            if (m2 == 0) srm[cl3] = a + brm[col];
            else         sh[cl3]  = tanh_fast(a + brr[col]);
        }
        __syncthreads();
    }
}

// g = r@W_rg + b_rg + qh@W_qg + b_qg  (bf16 [col][d] weights, contiguous reads)
__global__ void k_final2(const float* __restrict__ r, const float* __restrict__ qh,
                         const __bf16* __restrict__ wrgT, const __bf16* __restrict__ wqgT,
                         const float* __restrict__ brg, const float* __restrict__ bqg,
                         float* __restrict__ out) {
    int clx = threadIdx.x & 7, b = threadIdx.x >> 3;
    int col = blockIdx.x * 8 + clx;
    const __bf16* w1 = wrgT + (size_t)col * DIMD;
    const __bf16* w2 = wqgT + (size_t)col * DIMD;
    const float* rp = r + (size_t)b * DIMD;
    const float* qp = qh + (size_t)b * DIMD;
    float acc = brg[col] + bqg[col];
#pragma unroll 4
    for (int d = 0; d < DIMD; d += 8) {
        bf16x8 a = *(const bf16x8*)(w1 + d);
        bf16x8 c = *(const bf16x8*)(w2 + d);
#pragma unroll
        for (int u = 0; u < 8; u++)
            acc += rp[d + u] * (float)a[u] + qp[d + u] * (float)c[u];
    }
    out[b * DIMD + col] = acc;
}

// ---------------- host ----------------

extern "C" void kernel_launch(void* const* d_in, const int* in_sizes, int n_in,
                              void* d_out, int out_size, void* d_ws, size_t ws_size,
                              hipStream_t stream) {
    const float* ctx_in = (const float*)d_in[0];
    const float* q_in   = (const float*)d_in[1];
    const float* qh     = (const float*)d_in[2];
    const float* img    = (const float*)d_in[3];
    const float* W_fc1  = (const float*)d_in[4];
    const float* b_fc1  = (const float*)d_in[5];
    const float* W_fc2  = (const float*)d_in[6];
    const float* b_fc2  = (const float*)d_in[7];
    const float* W_dm   = (const float*)d_in[8];
    const float* b_dm   = (const float*)d_in[9];
    const float* W_rm   = (const float*)d_in[10];
    const float* b_rm   = (const float*)d_in[11];
    const float* W_qm   = (const float*)d_in[12];
    const float* b_qm   = (const float*)d_in[13];
    const float* W_rr   = (const float*)d_in[14];
    const float* b_rr   = (const float*)d_in[15];
    const float* W_rg   = (const float*)d_in[16];
    const float* b_rg   = (const float*)d_in[17];
    const float* W_qg   = (const float*)d_in[18];
    const float* b_qg   = (const float*)d_in[19];
    const float* W_ms   = (const float*)d_in[20];
    // d_in[21] = b_ms: unused (softmax shift-invariant)

    // workspace layout. RULE: x-region aliases acat -> only WRITTEN after g1
    // consumed acat (round-8 NaN was a violation of this rule).
    char* w = (char*)d_ws;
    __bf16* acat  = (__bf16*)w;  w += (size_t)8192 * 1024 * 2;   // 16.78 MB, dead after g1
    __bf16* qp    = (__bf16*)w;  w += (size_t)1024 * 512 * 2;
    __bf16* wcatT = (__bf16*)w;  w += (size_t)512 * 1024 * 2;
    __bf16* wdmT  = (__bf16*)w;  w += (size_t)512 * 512 * 2;
    __bf16* wqmT  = (__bf16*)w;  w += (size_t)512 * 512 * 2;
    __bf16* wrmT  = (__bf16*)w;  w += (size_t)512 * 512 * 2;
    __bf16* wrrT  = (__bf16*)w;  w += (size_t)512 * 512 * 2;
    __bf16* ctxb  = (__bf16*)w;  w += (size_t)8192 * 512 * 2;
    __bf16* ctxdm = (__bf16*)w;  w += (size_t)8192 * 512 * 2;
    // sub-allocate dead acat region (written only after g1 consumed it)
    char* x = (char*)acat;
    __bf16* ctxT  = (__bf16*)x;  x += (size_t)NB * DIMD * NS * 2;  // 8.39 MB
    float*  qmf   = (float*)x;   x += (size_t)1024 * 512 * 4;      // 2.10 MB
    __bf16* wrgT  = (__bf16*)x;  x += (size_t)512 * 512 * 2;
    __bf16* wqgT  = (__bf16*)x;  x += (size_t)512 * 512 * 2;
    u64*    rpub  = (u64*)x;     x += (size_t)NB * DIMD * 8;       // 128 KB tagged
    u64*    parts = (u64*)x;     x += (size_t)NB * 8 * NS * 8;     // 512 KB tagged
    float*  rbuf  = (float*)x;   x += (size_t)NB * DIMD * 4;       //  64 KB

    // fused prep: acat + qp + all six pre-GEMM weight transposes (1 launch)
    k_prep_all<<<11776, 256, 0, stream>>>(ctx_in, img, q_in, W_fc1, W_fc2, W_dm,
                                          W_qm, W_rm, W_rr, acat, qp,
                                          wcatT, wdmT, wqmT, wrmT, wrrT);
    // g1: ctx = acat @ W_cat^T + bfc1 + bfc2   (consumes acat)
    k_gemm64<<<dim3(128, 8), 256, 0, stream>>>(acat, wcatT, b_fc1, b_fc2, ctxb, 8192, 512, 1024, 0);
    // acat dead: ctxT + W_rg/W_qg transposes into its place
    k_post_t<<<dim3(16, 16, 34), dim3(32, 8), 0, stream>>>(ctxb, ctxT, W_rg, W_qg, wrgT, wqgT);
    // g2: ctxdm = ctxb @ W_dm^T + bdm
    k_gemm64<<<dim3(128, 8), 256, 0, stream>>>(ctxb, wdmT, b_dm, nullptr, ctxdm, 8192, 512, 512, 0);
    // qm = q @ W_qm^T + bqm (fp32 out)
    k_gemm64<<<dim3(16, 8), 256, 0, stream>>>(qp, wqmT, b_qm, nullptr, qmf, 1024, 512, 512, 1);

    // full-machine scan: 256 blocks (8 per batch) x 512 threads, tagged sync
    // (no flag memset needed: tags 1..32 never equal the 0xAA poison)
    k_scan<<<256, 512, 0, stream>>>(ctxdm, ctxT, wrmT, wrrT, qmf, W_ms,
                                    b_rm, b_rr, parts, rpub, rbuf);

    k_final2<<<64, 256, 0, stream>>>(rbuf, qh, wrgT, wqgT, b_rg, b_qg, (float*)d_out);
}

// Round 12
// 447.726 us; speedup vs baseline: 1.1728x; 1.0442x over previous
//
#include <hip/hip_runtime.h>
#include <hip/hip_bf16.h>

// Problem dims (fixed by reference): D=512, B=32, S_c=256, S_q(T)=32
#define DIMD 512
#define NB   32
#define NS   256
#define NT   32
// LDS strides chosen for bank-conflict freedom (dword-stride ≡ 1/2 mod 32)
#define SA_STR  66    // ctxdm slice rows (bf16): 132B = 33 dw ≡ 1
#define SCT_STR 258   // ctxT slice rows (bf16): 516B = 129 dw ≡ 1
#define SR_STR  132   // r chunks (fp32): 132 dw ≡ 4 -> q-groups on distinct banks

typedef __bf16 bf16x8 __attribute__((ext_vector_type(8)));
typedef float  f32x4  __attribute__((ext_vector_type(4)));
typedef unsigned long long u64;

__device__ __forceinline__ float tanh_fast(float x) {
    float e = __expf(2.f * x);
    return 1.f - 2.f / (e + 1.f);
}

// async global->LDS, 16B per lane; lds dest = wave-uniform base + lane*16
__device__ __forceinline__ void gl_lds16(const __bf16* g, __bf16* l) {
    __builtin_amdgcn_global_load_lds((const __attribute__((address_space(1))) void*)g,
                                     (__attribute__((address_space(3))) void*)l, 16, 0, 0);
}

// ---- tagged-data sync: {value,tag} in one 64-bit relaxed atomic. No flags, no
// fences, no vmcnt drains; causality via data dependence (proven round 10).
// Tags 1..NT never collide with the 0xAAAAAAAA workspace poison.
__device__ __forceinline__ void pub64(u64* p, float v, unsigned tag) {
    u64 pk = ((u64)__float_as_uint(v) << 32) | (u64)tag;
    __hip_atomic_store(p, pk, __ATOMIC_RELAXED, __HIP_MEMORY_SCOPE_AGENT);
}
__device__ __forceinline__ float poll64(const u64* p, unsigned tag) {
    u64 v = __hip_atomic_load(p, __ATOMIC_RELAXED, __HIP_MEMORY_SCOPE_AGENT);
    while ((unsigned)v != tag) {
        __builtin_amdgcn_s_sleep(1);
        v = __hip_atomic_load(p, __ATOMIC_RELAXED, __HIP_MEMORY_SCOPE_AGENT);
    }
    return __uint_as_float((unsigned)(v >> 32));
}

// ---------------- fused prep: acat + q cast + EIGHT weight transposes ----------------
// blocks 0..8191: acat rows; 8192..10239: q fp32->bf16; 10240..12287: transposes
__global__ void k_prep_all(const float* __restrict__ ctxin, const float* __restrict__ img,
                           const float* __restrict__ qin,
                           const float* __restrict__ Wfc1, const float* __restrict__ Wfc2,
                           const float* __restrict__ Wdm, const float* __restrict__ Wqm,
                           const float* __restrict__ Wrm, const float* __restrict__ Wrr,
                           const float* __restrict__ Wrg, const float* __restrict__ Wqg,
                           __bf16* __restrict__ acat, __bf16* __restrict__ qp,
                           __bf16* __restrict__ wcatT, __bf16* __restrict__ wdmT,
                           __bf16* __restrict__ wqmT, __bf16* __restrict__ wrmT,
                           __bf16* __restrict__ wrrT, __bf16* __restrict__ wrgT,
                           __bf16* __restrict__ wqgT) {
    int row = blockIdx.x;
    if (row < 8192) {
        int b = row >> 8, s = row & 255;
        const float* c  = ctxin + ((size_t)s * NB + b) * DIMD;
        const float* im = img   + ((size_t)s * NB + b) * DIMD;
        __bf16* o = acat + (size_t)row * 1024;
        for (int d = threadIdx.x; d < DIMD; d += 256) {
            o[d]       = (__bf16)c[d];
            o[512 + d] = (__bf16)im[d];
        }
    } else if (row < 10240) {
        int idx = (row - 8192) * 256 + threadIdx.x;   // 2048*256 = NT*NB*DIMD
        qp[idx] = (__bf16)qin[idx];
    } else {
        __shared__ float tile[32][33];
        int zz = (row - 10240) >> 8;       // matrix id 0..7
        int idx = (row - 10240) & 255;
        int bx = idx & 15, by = idx >> 4;
        int x = threadIdx.x & 31, y = threadIdx.x >> 5;   // 32 x 8
        const float* src = (zz == 0) ? Wfc1 : (zz == 1) ? Wfc2 : (zz == 2) ? Wdm
                         : (zz == 3) ? Wqm : (zz == 4) ? Wrm : (zz == 5) ? Wrr
                         : (zz == 6) ? Wrg : Wqg;
        __bf16* dst; int stride, off;
        if (zz < 2) { dst = wcatT; stride = 1024; off = zz * 512; }
        else {
            dst = (zz == 2) ? wdmT : (zz == 3) ? wqmT : (zz == 4) ? wrmT
                : (zz == 5) ? wrrT : (zz == 6) ? wrgT : wqgT;
            stride = 512; off = 0;
        }
        int c0 = bx * 32, r0 = by * 32;
#pragma unroll
        for (int k = 0; k < 32; k += 8)
            tile[y + k][x] = src[(size_t)(r0 + y + k) * DIMD + c0 + x];
        __syncthreads();
#pragma unroll
        for (int k = 0; k < 32; k += 8)
            dst[(size_t)(c0 + y + k) * stride + off + r0 + x] = (__bf16)tile[x][y + k];
    }
}

// ---------------- shared GEMM tile body (64x64, 4 waves, K-step 64) ----------------
__device__ __forceinline__ void gemm_tile(const __bf16* __restrict__ A,
                                          const __bf16* __restrict__ BT,
                                          const float* __restrict__ bias1,
                                          const float* __restrict__ bias2,
                                          void* __restrict__ out, int N, int K,
                                          int m0, int n0, int out_f32,
                                          __bf16* As, __bf16* Bs) {
    int tid = threadIdx.x, wave = tid >> 6, lane = tid & 63;
    int wm = wave >> 1, wn = wave & 1;
    int lr = lane & 15, lq = lane >> 4;

    f32x4 acc[2][2];
#pragma unroll
    for (int i = 0; i < 2; i++)
#pragma unroll
        for (int j = 0; j < 2; j++) acc[i][j] = (f32x4){0.f, 0.f, 0.f, 0.f};

    int g0 = (wave * 2 + 0) * 64 + lane;
    int g1 = (wave * 2 + 1) * 64 + lane;
    int r0_ = g0 >> 3, c0_ = g0 & 7;
    int r1_ = g1 >> 3, c1_ = g1 & 7;
    __bf16* la0 = As + (wave * 2 + 0) * 512;
    __bf16* la1 = As + (wave * 2 + 1) * 512;
    __bf16* lb0 = Bs + (wave * 2 + 0) * 512;
    __bf16* lb1 = Bs + (wave * 2 + 1) * 512;

    for (int kk = 0; kk < K; kk += 64) {
        gl_lds16(A  + (size_t)(m0 + r0_) * K + kk + c0_ * 8, la0);
        gl_lds16(A  + (size_t)(m0 + r1_) * K + kk + c1_ * 8, la1);
        gl_lds16(BT + (size_t)(n0 + r0_) * K + kk + c0_ * 8, lb0);
        gl_lds16(BT + (size_t)(n0 + r1_) * K + kk + c1_ * 8, lb1);
        __syncthreads();
#pragma unroll
        for (int k2 = 0; k2 < 64; k2 += 32) {
            bf16x8 af[2], bfv[2];
#pragma unroll
            for (int i = 0; i < 2; i++)
                af[i] = *(const bf16x8*)(As + (wm * 32 + i * 16 + lr) * 64 + k2 + lq * 8);
#pragma unroll
            for (int j = 0; j < 2; j++)
                bfv[j] = *(const bf16x8*)(Bs + (wn * 32 + j * 16 + lr) * 64 + k2 + lq * 8);
#pragma unroll
            for (int i = 0; i < 2; i++)
#pragma unroll
                for (int j = 0; j < 2; j++)
                    acc[i][j] = __builtin_amdgcn_mfma_f32_16x16x32_bf16(af[i], bfv[j], acc[i][j], 0, 0, 0);
        }
        __syncthreads();
    }

#pragma unroll
    for (int i = 0; i < 2; i++)
#pragma unroll
        for (int j = 0; j < 2; j++) {
            int col = n0 + wn * 32 + j * 16 + lr;
            float bs = (bias1 ? bias1[col] : 0.f) + (bias2 ? bias2[col] : 0.f);
#pragma unroll
            for (int r = 0; r < 4; r++) {
                int row = m0 + wm * 32 + i * 16 + lq * 4 + r;
                float v = acc[i][j][r] + bs;
                if (out_f32) ((float*)out)[(size_t)row * N + col] = v;
                else         ((__bf16*)out)[(size_t)row * N + col] = (__bf16)v;
            }
        }
}

// g1: ctx = acat @ W_cat^T + bfc1 + bfc2
__global__ void k_gemm64(const __bf16* __restrict__ A, const __bf16* __restrict__ BT,
                         const float* __restrict__ bias1, const float* __restrict__ bias2,
                         void* __restrict__ out, int M, int N, int K, int out_f32) {
    __shared__ __bf16 As[64 * 64];
    __shared__ __bf16 Bs[64 * 64];
    gemm_tile(A, BT, bias1, bias2, out, N, K, blockIdx.x * 64, blockIdx.y * 64, out_f32, As, Bs);
}

// fused post-g1 work, one launch (all depend only on g1/prep outputs):
// blocks 0..1023: g2 (ctxdm = ctxb@wdmT + bdm); 1024..1151: qm GEMM;
// 1152..5247: ctxT per-batch transpose
__global__ void k_fused(const __bf16* __restrict__ ctxb, const __bf16* __restrict__ wdmT,
                        const float* __restrict__ bdm, __bf16* __restrict__ ctxdm,
                        const __bf16* __restrict__ qp, const __bf16* __restrict__ wqmT,
                        const float* __restrict__ bqm, float* __restrict__ qmf,
                        __bf16* __restrict__ ctxT) {
    __shared__ __bf16 As[64 * 64];
    __shared__ __bf16 Bs[64 * 64];
    int bid = blockIdx.x;
    if (bid < 1024) {
        gemm_tile(ctxb, wdmT, bdm, nullptr, ctxdm, 512, 512,
                  (bid & 127) * 64, (bid >> 7) * 64, 0, As, Bs);
    } else if (bid < 1152) {
        int b2 = bid - 1024;
        gemm_tile(qp, wqmT, bqm, nullptr, qmf, 512, 512,
                  (b2 & 15) * 64, (b2 >> 4) * 64, 1, As, Bs);
    } else {
        int b3 = bid - 1152;
        int z = b3 >> 7, rest = b3 & 127;
        int c0 = (rest & 15) * 32, s0 = (rest >> 4) * 32;
        __bf16* tile = As;   // reuse gemm LDS as [32][33] bf16 tile
        int x = threadIdx.x & 31, y = threadIdx.x >> 5;   // 32 x 8
        const __bf16* S = ctxb + (size_t)z * NS * DIMD;
        __bf16* D = ctxT + (size_t)z * DIMD * NS;
#pragma unroll
        for (int k = 0; k < 32; k += 8)
            tile[(y + k) * 33 + x] = S[(size_t)(s0 + y + k) * DIMD + c0 + x];
        __syncthreads();
#pragma unroll
        for (int k = 0; k < 32; k += 8)
            D[(size_t)(c0 + y + k) * NS + s0 + x] = tile[x * 33 + y + k];
    }
}

// ---------------- scan: 8 blocks/batch, tagged-data sync, on-chip state ----------------
// grid 256 = 32 batches x 8 e-slices; block 512 threads (8 waves), 1 block/CU.
// XCD-affinity: b = bid&31, j = bid>>5 (halved scan FETCH, round 9).
__global__ __launch_bounds__(512, 2) void k_scan(
    const __bf16* __restrict__ ctxdm,  // [b*256+s][512]
    const __bf16* __restrict__ ctxT,   // [b][c][s]
    const __bf16* __restrict__ wrmT,   // [c][d]
    const __bf16* __restrict__ wrrT,   // [c][d]
    const float* __restrict__ qmf,     // [t*32+b][512]
    const float* __restrict__ wms, const float* __restrict__ brm,
    const float* __restrict__ brr,
    u64* parts,                        // [b][8][256] tagged
    u64* rpub,                         // [b][512] tagged
    float* __restrict__ rbuf) {
    int bid = blockIdx.x;
    int b = bid & 31, j = bid >> 5;        // XCD-affinity mapping
    int tid = threadIdx.x, wave = tid >> 6, lane = tid & 63;
    int g = lane >> 3, i = lane & 7;       // s-subgroup, e-chunk

    __shared__ __bf16 sA[256 * SA_STR];    // 33.8 KB (ctxdm slice)
    __shared__ __bf16 sCT[64 * SCT_STR];   // 33.0 KB (ctxT slice)
    __shared__ float  sQ[NT * 64];         //  8 KB
    __shared__ float  sq[512];             // B1 gather sums
    __shared__ float  sp[256];             // exp values (separate from sq: race fix)
    __shared__ float  s4[4];
    __shared__ float  sps[8 * 68];         // B1 per-wave partials (stride 68)
    __shared__ float  srm[64], sh[64];
    __shared__ float  sr4[4 * SR_STR];     // r in 4 padded chunks
    __shared__ float  smv[512];

    // ---- one-time staging ----
    for (int c = tid; c < 2048; c += 512) {            // sA: 256 rows x 64 e
        int row = c >> 3, c8 = c & 7;
        *(bf16x8*)(sA + row * SA_STR + c8 * 8) =
            *(const bf16x8*)(ctxdm + ((size_t)(b * NS + row)) * DIMD + j * 64 + c8 * 8);
    }
    for (int c = tid; c < 2048; c += 512) {            // sCT: 64 cols x 256 s
        int col = c >> 5, s8 = c & 31;
        *(bf16x8*)(sCT + col * SCT_STR + s8 * 8) =
            *(const bf16x8*)(ctxT + ((size_t)(b * DIMD) + j * 64 + col) * NS + s8 * 8);
    }
    for (int c = tid; c < NT * 64; c += 512) {         // sQ
        int tt = c >> 6, e = c & 63;
        sQ[c] = qmf[((size_t)tt * NB + b) * DIMD + j * 64 + e];
    }
    // weight slice -> registers: thread (m,cl,q) owns d in [q*128,(q+1)*128)
    int m = tid >> 8, cl = (tid >> 2) & 63, q = tid & 3;
    const __bf16* wp = (m ? wrrT : wrmT) + ((size_t)(j * 64 + cl)) * DIMD + q * 128;
    bf16x8 wreg[16];
#pragma unroll
    for (int u = 0; u < 16; u++) wreg[u] = *(const bf16x8*)(wp + u * 8);

    float wm[8];
#pragma unroll
    for (int u = 0; u < 8; u++) wm[u] = wms[j * 64 + i * 8 + u];
    if (tid < 64) {
        srm[tid] = brm[j * 64 + tid];            // rm_0 slice (r0 = 0)
        sh[tid]  = tanh_fast(brr[j * 64 + tid]); // h_0 slice
    }
    __syncthreads();

    for (int t = 0; t < NT; t++) {
        unsigned tag = (unsigned)(t + 1);
        // ---- phase A: partial logits over own e-slice, published DIRECTLY from
        // the loop (no LDS round-trip / no syncthreads: early waves publish
        // sooner, shrinking the exchange tail; self-sync via polling own tags) ----
        float rq[8];
#pragma unroll
        for (int u = 0; u < 8; u++) rq[u] = srm[i * 8 + u] + sQ[t * 64 + i * 8 + u];
#pragma unroll
        for (int k = 0; k < 4; k++) {
            int s = wave * 32 + k * 8 + g;
            bf16x8 cv = *(const bf16x8*)(sA + s * SA_STR + i * 8);
            float a = 0.f;
#pragma unroll
            for (int u = 0; u < 8; u++)
                a += tanh_fast((float)cv[u] + rq[u]) * wm[u];
            a += __shfl_xor(a, 1); a += __shfl_xor(a, 2); a += __shfl_xor(a, 4);
            if (i == 0) pub64(&parts[(b * 8 + j) * NS + s], a, tag);
        }

        // ---- phase B1: batched poll of 4 partial slices (concurrent loads),
        // softmax, weighted ctx sum -> r-slice ----
        {
            int s = tid >> 1, jh = (tid & 1) * 4;
            const u64* p0 = &parts[(b * 8 + jh + 0) * NS + s];
            const u64* p1 = &parts[(b * 8 + jh + 1) * NS + s];
            const u64* p2 = &parts[(b * 8 + jh + 2) * NS + s];
            const u64* p3 = &parts[(b * 8 + jh + 3) * NS + s];
            u64 v0, v1, v2, v3;
            for (;;) {
                v0 = __hip_atomic_load(p0, __ATOMIC_RELAXED, __HIP_MEMORY_SCOPE_AGENT);
                v1 = __hip_atomic_load(p1, __ATOMIC_RELAXED, __HIP_MEMORY_SCOPE_AGENT);
                v2 = __hip_atomic_load(p2, __ATOMIC_RELAXED, __HIP_MEMORY_SCOPE_AGENT);
                v3 = __hip_atomic_load(p3, __ATOMIC_RELAXED, __HIP_MEMORY_SCOPE_AGENT);
                if ((unsigned)v0 == tag && (unsigned)v1 == tag &&
                    (unsigned)v2 == tag && (unsigned)v3 == tag) break;
                __builtin_amdgcn_s_sleep(1);
            }
            sq[tid] = __uint_as_float((unsigned)(v0 >> 32)) + __uint_as_float((unsigned)(v1 >> 32))
                    + __uint_as_float((unsigned)(v2 >> 32)) + __uint_as_float((unsigned)(v3 >> 32));
        }
        __syncthreads();
        float ev = 0.f;
        if (tid < NS) { ev = __expf(sq[2 * tid] + sq[2 * tid + 1]); sp[tid] = ev; }
#pragma unroll
        for (int off = 32; off; off >>= 1) ev += __shfl_xor(ev, off);
        if (tid < NS && lane == 0) s4[wave] = ev;
        __syncthreads();
        float inv = 1.f / (s4[0] + s4[1] + s4[2] + s4[3]);
        {
            // wave = s-chunk, lane = col: per-lane linear LDS streams (2-way max)
            const __bf16* cp = sCT + lane * SCT_STR + wave * 32;
            const float* pp = sp + wave * 32;
            float a = 0.f;
#pragma unroll
            for (int k = 0; k < 32; k += 8) {
                bf16x8 v = *(const bf16x8*)(cp + k);
#pragma unroll
                for (int u = 0; u < 8; u++) a = fmaf(pp[k + u], (float)v[u], a);
            }
            sps[wave * 68 + lane] = a;
        }
        __syncthreads();
        if (tid < 64) {
            float a = 0.f;
#pragma unroll
            for (int w2 = 0; w2 < 8; w2++) a += sps[w2 * 68 + tid];
            float rv = a * inv + sh[tid];
            if (t == NT - 1) rbuf[b * DIMD + j * 64 + tid] = rv;   // final r
            else             pub64(&rpub[b * DIMD + j * 64 + tid], rv, tag);
        }
        if (t == NT - 1) break;            // no consumers after last step

        // ---- phase B2: poll r, register-weight matvec -> rm/h (block-local) ----
        sr4[(tid >> 7) * SR_STR + (tid & 127)] = poll64(&rpub[b * DIMD + tid], tag);
        __syncthreads();
        {
            const float* sv = sr4 + q * SR_STR;   // q-groups land on distinct banks
            float a0 = 0.f, a1 = 0.f;
#pragma unroll
            for (int u = 0; u < 16; u += 2) {
                bf16x8 w0 = wreg[u], w1 = wreg[u + 1];
#pragma unroll
                for (int e = 0; e < 8; e++) {
                    a0 = fmaf(sv[u * 8 + e],     (float)w0[e], a0);
                    a1 = fmaf(sv[u * 8 + 8 + e], (float)w1[e], a1);
                }
            }
            smv[tid] = a0 + a1;
        }
        __syncthreads();
        if (tid < 128) {
            int m2 = tid >> 6, cl3 = tid & 63;
            float a = smv[m2 * 256 + cl3 * 4] + smv[m2 * 256 + cl3 * 4 + 1]
                    + smv[m2 * 256 + cl3 * 4 + 2] + smv[m2 * 256 + cl3 * 4 + 3];
            int col = j * 64 + cl3;
            if (m2 == 0) srm[cl3] = a + brm[col];
            else         sh[cl3]  = tanh_fast(a + brr[col]);
        }
        __syncthreads();
    }
}

// g = r@W_rg + b_rg + qh@W_qg + b_qg  (bf16 [col][d] weights, contiguous reads)
__global__ void k_final2(const float* __restrict__ r, const float* __restrict__ qh,
                         const __bf16* __restrict__ wrgT, const __bf16* __restrict__ wqgT,
                         const float* __restrict__ brg, const float* __restrict__ bqg,
                         float* __restrict__ out) {
    int clx = threadIdx.x & 7, b = threadIdx.x >> 3;
    int col = blockIdx.x * 8 + clx;
    const __bf16* w1 = wrgT + (size_t)col * DIMD;
    const __bf16* w2 = wqgT + (size_t)col * DIMD;
    const float* rp = r + (size_t)b * DIMD;
    const float* qp = qh + (size_t)b * DIMD;
    float acc = brg[col] + bqg[col];
#pragma unroll 4
    for (int d = 0; d < DIMD; d += 8) {
        bf16x8 a = *(const bf16x8*)(w1 + d);
        bf16x8 c = *(const bf16x8*)(w2 + d);
#pragma unroll
        for (int u = 0; u < 8; u++)
            acc += rp[d + u] * (float)a[u] + qp[d + u] * (float)c[u];
    }
    out[b * DIMD + col] = acc;
}

// ---------------- host ----------------

extern "C" void kernel_launch(void* const* d_in, const int* in_sizes, int n_in,
                              void* d_out, int out_size, void* d_ws, size_t ws_size,
                              hipStream_t stream) {
    const float* ctx_in = (const float*)d_in[0];
    const float* q_in   = (const float*)d_in[1];
    const float* qh     = (const float*)d_in[2];
    const float* img    = (const float*)d_in[3];
    const float* W_fc1  = (const float*)d_in[4];
    const float* b_fc1  = (const float*)d_in[5];
    const float* W_fc2  = (const float*)d_in[6];
    const float* b_fc2  = (const float*)d_in[7];
    const float* W_dm   = (const float*)d_in[8];
    const float* b_dm   = (const float*)d_in[9];
    const float* W_rm   = (const float*)d_in[10];
    const float* b_rm   = (const float*)d_in[11];
    const float* W_qm   = (const float*)d_in[12];
    const float* b_qm   = (const float*)d_in[13];
    const float* W_rr   = (const float*)d_in[14];
    const float* b_rr   = (const float*)d_in[15];
    const float* W_rg   = (const float*)d_in[16];
    const float* b_rg   = (const float*)d_in[17];
    const float* W_qg   = (const float*)d_in[18];
    const float* b_qg   = (const float*)d_in[19];
    const float* W_ms   = (const float*)d_in[20];
    // d_in[21] = b_ms: unused (softmax shift-invariant)

    // workspace layout (38.78 MB main chain). RULE: x-region aliases acat ->
    // only WRITTEN after g1 consumed acat (round-8 NaN was a violation).
    // wrgT/wqgT are written by prep (before g1) -> main chain, NOT x-region.
    char* w = (char*)d_ws;
    __bf16* acat  = (__bf16*)w;  w += (size_t)8192 * 1024 * 2;   // 16.78 MB, dead after g1
    __bf16* qp    = (__bf16*)w;  w += (size_t)1024 * 512 * 2;
    __bf16* wcatT = (__bf16*)w;  w += (size_t)512 * 1024 * 2;
    __bf16* wdmT  = (__bf16*)w;  w += (size_t)512 * 512 * 2;
    __bf16* wqmT  = (__bf16*)w;  w += (size_t)512 * 512 * 2;
    __bf16* wrmT  = (__bf16*)w;  w += (size_t)512 * 512 * 2;
    __bf16* wrrT  = (__bf16*)w;  w += (size_t)512 * 512 * 2;
    __bf16* wrgT  = (__bf16*)w;  w += (size_t)512 * 512 * 2;
    __bf16* wqgT  = (__bf16*)w;  w += (size_t)512 * 512 * 2;
    __bf16* ctxb  = (__bf16*)w;  w += (size_t)8192 * 512 * 2;
    __bf16* ctxdm = (__bf16*)w;  w += (size_t)8192 * 512 * 2;
    // sub-allocate dead acat region (written only after g1 consumed it)
    char* x = (char*)acat;
    __bf16* ctxT  = (__bf16*)x;  x += (size_t)NB * DIMD * NS * 2;  // 8.39 MB
    float*  qmf   = (float*)x;   x += (size_t)1024 * 512 * 4;      // 2.10 MB
    u64*    rpub  = (u64*)x;     x += (size_t)NB * DIMD * 8;       // 128 KB tagged
    u64*    parts = (u64*)x;     x += (size_t)NB * 8 * NS * 8;     // 512 KB tagged
    float*  rbuf  = (float*)x;   x += (size_t)NB * DIMD * 4;       //  64 KB

    // 1. fused prep: acat + qp + all EIGHT weight transposes
    k_prep_all<<<12288, 256, 0, stream>>>(ctx_in, img, q_in, W_fc1, W_fc2, W_dm,
                                          W_qm, W_rm, W_rr, W_rg, W_qg, acat, qp,
                                          wcatT, wdmT, wqmT, wrmT, wrrT, wrgT, wqgT);
    // 2. g1: ctx = acat @ W_cat^T + bfc1 + bfc2   (consumes acat)
    k_gemm64<<<dim3(128, 8), 256, 0, stream>>>(acat, wcatT, b_fc1, b_fc2, ctxb, 8192, 512, 1024, 0);
    // 3. fused post-g1: g2 GEMM + qm GEMM + ctxT transpose (acat now dead)
    k_fused<<<5248, 256, 0, stream>>>(ctxb, wdmT, b_dm, ctxdm, qp, wqmT, b_qm, qmf, ctxT);
    // 4. full-machine scan: 256 blocks (8 per batch) x 512 threads, tagged sync
    k_scan<<<256, 512, 0, stream>>>(ctxdm, ctxT, wrmT, wrrT, qmf, W_ms,
                                    b_rm, b_rr, parts, rpub, rbuf);
    // 5. final
    k_final2<<<64, 256, 0, stream>>>(rbuf, qh, wrgT, wqgT, b_rg, b_qg, (float*)d_out);
}

// Round 13
// 433.566 us; speedup vs baseline: 1.2111x; 1.0327x over previous
//
#include <hip/hip_runtime.h>
#include <hip/hip_bf16.h>

// Problem dims (fixed by reference): D=512, B=32, S_c=256, S_q(T)=32
#define DIMD 512
#define NB   32
#define NS   256
#define NT   32
// LDS strides chosen for bank-conflict freedom (dword-stride ≡ 1/2 mod 32)
#define SA_STR  66    // ctxdm slice rows (bf16): 132B = 33 dw ≡ 1
#define SCT_STR 258   // ctxT slice rows (bf16): 516B = 129 dw ≡ 1
#define SR_STR  132   // r chunks (fp32): 132 dw ≡ 4 -> q-groups on distinct banks

typedef __bf16 bf16x8 __attribute__((ext_vector_type(8)));
typedef float  f32x4  __attribute__((ext_vector_type(4)));
typedef unsigned long long u64;

__device__ __forceinline__ float tanh_fast(float x) {
    float e = __expf(2.f * x);
    return 1.f - 2.f / (e + 1.f);
}

// async global->LDS, 16B per lane; lds dest = wave-uniform base + lane*16
__device__ __forceinline__ void gl_lds16(const __bf16* g, __bf16* l) {
    __builtin_amdgcn_global_load_lds((const __attribute__((address_space(1))) void*)g,
                                     (__attribute__((address_space(3))) void*)l, 16, 0, 0);
}

// ---- tagged-data sync: {value,tag} in one 64-bit relaxed atomic (proven r10-12).
// Tags 1..NT never collide with the 0xAAAAAAAA workspace poison.
__device__ __forceinline__ void pub64(u64* p, float v, unsigned tag) {
    u64 pk = ((u64)__float_as_uint(v) << 32) | (u64)tag;
    __hip_atomic_store(p, pk, __ATOMIC_RELAXED, __HIP_MEMORY_SCOPE_AGENT);
}
__device__ __forceinline__ float poll64(const u64* p, unsigned tag) {
    u64 v = __hip_atomic_load(p, __ATOMIC_RELAXED, __HIP_MEMORY_SCOPE_AGENT);
    while ((unsigned)v != tag) {
        __builtin_amdgcn_s_sleep(1);
        v = __hip_atomic_load(p, __ATOMIC_RELAXED, __HIP_MEMORY_SCOPE_AGENT);
    }
    return __uint_as_float((unsigned)(v >> 32));
}

// ---------------- fused prep: acat + q cast + EIGHT weight transposes ----------------
__global__ void k_prep_all(const float* __restrict__ ctxin, const float* __restrict__ img,
                           const float* __restrict__ qin,
                           const float* __restrict__ Wfc1, const float* __restrict__ Wfc2,
                           const float* __restrict__ Wdm, const float* __restrict__ Wqm,
                           const float* __restrict__ Wrm, const float* __restrict__ Wrr,
                           const float* __restrict__ Wrg, const float* __restrict__ Wqg,
                           __bf16* __restrict__ acat, __bf16* __restrict__ qp,
                           __bf16* __restrict__ wcatT, __bf16* __restrict__ wdmT,
                           __bf16* __restrict__ wqmT, __bf16* __restrict__ wrmT,
                           __bf16* __restrict__ wrrT, __bf16* __restrict__ wrgT,
                           __bf16* __restrict__ wqgT) {
    int row = blockIdx.x;
    if (row < 8192) {
        int b = row >> 8, s = row & 255;
        const float* c  = ctxin + ((size_t)s * NB + b) * DIMD;
        const float* im = img   + ((size_t)s * NB + b) * DIMD;
        __bf16* o = acat + (size_t)row * 1024;
        for (int d = threadIdx.x; d < DIMD; d += 256) {
            o[d]       = (__bf16)c[d];
            o[512 + d] = (__bf16)im[d];
        }
    } else if (row < 10240) {
        int idx = (row - 8192) * 256 + threadIdx.x;   // 2048*256 = NT*NB*DIMD
        qp[idx] = (__bf16)qin[idx];
    } else {
        __shared__ float tile[32][33];
        int zz = (row - 10240) >> 8;       // matrix id 0..7
        int idx = (row - 10240) & 255;
        int bx = idx & 15, by = idx >> 4;
        int x = threadIdx.x & 31, y = threadIdx.x >> 5;   // 32 x 8
        const float* src = (zz == 0) ? Wfc1 : (zz == 1) ? Wfc2 : (zz == 2) ? Wdm
                         : (zz == 3) ? Wqm : (zz == 4) ? Wrm : (zz == 5) ? Wrr
                         : (zz == 6) ? Wrg : Wqg;
        __bf16* dst; int stride, off;
        if (zz < 2) { dst = wcatT; stride = 1024; off = zz * 512; }
        else {
            dst = (zz == 2) ? wdmT : (zz == 3) ? wqmT : (zz == 4) ? wrmT
                : (zz == 5) ? wrrT : (zz == 6) ? wrgT : wqgT;
            stride = 512; off = 0;
        }
        int c0 = bx * 32, r0 = by * 32;
#pragma unroll
        for (int k = 0; k < 32; k += 8)
            tile[y + k][x] = src[(size_t)(r0 + y + k) * DIMD + c0 + x];
        __syncthreads();
#pragma unroll
        for (int k = 0; k < 32; k += 8)
            dst[(size_t)(c0 + y + k) * stride + off + r0 + x] = (__bf16)tile[x][y + k];
    }
}

// ---------------- 128x128-tile GEMM body (round-3 proven pattern) ----------------
// 256 thr = 4 waves; wave tile 64x64 (4x4 of 16x16x32 MFMA); BK=32; LDS staged
// via global_load_lds width-16 (the m93->m97 874 TF structure).
__device__ __forceinline__ void gemm_tile128(const __bf16* __restrict__ A,
                                             const __bf16* __restrict__ BT,
                                             const float* __restrict__ bias1,
                                             const float* __restrict__ bias2,
                                             void* __restrict__ out, int N, int K,
                                             int m0, int n0, int out_f32,
                                             __bf16* As, __bf16* Bs) {
    int tid = threadIdx.x, wave = tid >> 6, lane = tid & 63;
    int wm_ = wave >> 1, wn = wave & 1;
    int lr = lane & 15, lq = lane >> 4;

    f32x4 acc[4][4];
#pragma unroll
    for (int i = 0; i < 4; i++)
#pragma unroll
        for (int j = 0; j < 4; j++) acc[i][j] = (f32x4){0.f, 0.f, 0.f, 0.f};

    // staging chunk ids: chunk g = (wave*2+i)*64 + lane covers row g>>2, k-quarter g&3
    int g0 = (wave * 2 + 0) * 64 + lane;
    int g1 = (wave * 2 + 1) * 64 + lane;
    int r0_ = g0 >> 2, c0_ = g0 & 3;
    int r1_ = g1 >> 2, c1_ = g1 & 3;
    __bf16* la0 = As + (wave * 2 + 0) * 512;   // +lane*16B added by HW
    __bf16* la1 = As + (wave * 2 + 1) * 512;
    __bf16* lb0 = Bs + (wave * 2 + 0) * 512;
    __bf16* lb1 = Bs + (wave * 2 + 1) * 512;

    for (int kk = 0; kk < K; kk += 32) {
        gl_lds16(A  + (size_t)(m0 + r0_) * K + kk + c0_ * 8, la0);
        gl_lds16(A  + (size_t)(m0 + r1_) * K + kk + c1_ * 8, la1);
        gl_lds16(BT + (size_t)(n0 + r0_) * K + kk + c0_ * 8, lb0);
        gl_lds16(BT + (size_t)(n0 + r1_) * K + kk + c1_ * 8, lb1);
        __syncthreads();
        bf16x8 af[4], bfv[4];
#pragma unroll
        for (int i = 0; i < 4; i++)
            af[i] = *(const bf16x8*)(As + (wm_ * 64 + i * 16 + lr) * 32 + lq * 8);
#pragma unroll
        for (int j = 0; j < 4; j++)
            bfv[j] = *(const bf16x8*)(Bs + (wn * 64 + j * 16 + lr) * 32 + lq * 8);
#pragma unroll
        for (int i = 0; i < 4; i++)
#pragma unroll
            for (int j = 0; j < 4; j++)
                acc[i][j] = __builtin_amdgcn_mfma_f32_16x16x32_bf16(af[i], bfv[j], acc[i][j], 0, 0, 0);
        __syncthreads();
    }

#pragma unroll
    for (int i = 0; i < 4; i++)
#pragma unroll
        for (int j = 0; j < 4; j++) {
            int col = n0 + wn * 64 + j * 16 + lr;
            float bs = (bias1 ? bias1[col] : 0.f) + (bias2 ? bias2[col] : 0.f);
#pragma unroll
            for (int r = 0; r < 4; r++) {
                int row = m0 + wm_ * 64 + i * 16 + lq * 4 + r;   // verified C/D layout
                float v = acc[i][j][r] + bs;
                if (out_f32) ((float*)out)[(size_t)row * N + col] = v;
                else         ((__bf16*)out)[(size_t)row * N + col] = (__bf16)v;
            }
        }
}

// g1: ctx = acat @ W_cat^T + bfc1 + bfc2  (128-tile)
__global__ void k_gemm128(const __bf16* __restrict__ A, const __bf16* __restrict__ BT,
                          const float* __restrict__ bias1, const float* __restrict__ bias2,
                          void* __restrict__ out, int M, int N, int K, int out_f32) {
    __shared__ __bf16 As[128 * 32];
    __shared__ __bf16 Bs[128 * 32];
    gemm_tile128(A, BT, bias1, bias2, out, N, K, blockIdx.x * 128, blockIdx.y * 128, out_f32, As, Bs);
}

// fused post-g1 work, one launch: blocks 0..255 g2 (128-tile);
// 256..287 qm GEMM (128-tile); 288..4383 ctxT per-batch transpose
__global__ void k_fused(const __bf16* __restrict__ ctxb, const __bf16* __restrict__ wdmT,
                        const float* __restrict__ bdm, __bf16* __restrict__ ctxdm,
                        const __bf16* __restrict__ qp, const __bf16* __restrict__ wqmT,
                        const float* __restrict__ bqm, float* __restrict__ qmf,
                        __bf16* __restrict__ ctxT) {
    __shared__ __bf16 As[128 * 32];
    __shared__ __bf16 Bs[128 * 32];
    int bid = blockIdx.x;
    if (bid < 256) {
        gemm_tile128(ctxb, wdmT, bdm, nullptr, ctxdm, 512, 512,
                     (bid & 63) * 128, (bid >> 6) * 128, 0, As, Bs);
    } else if (bid < 288) {
        int b2 = bid - 256;
        gemm_tile128(qp, wqmT, bqm, nullptr, qmf, 512, 512,
                     (b2 & 7) * 128, (b2 >> 3) * 128, 1, As, Bs);
    } else {
        int b3 = bid - 288;
        int z = b3 >> 7, rest = b3 & 127;
        int c0 = (rest & 15) * 32, s0 = (rest >> 4) * 32;
        __bf16* tile = As;   // reuse gemm LDS as [32][33] bf16 tile
        int x = threadIdx.x & 31, y = threadIdx.x >> 5;   // 32 x 8
        const __bf16* S = ctxb + (size_t)z * NS * DIMD;
        __bf16* D = ctxT + (size_t)z * DIMD * NS;
#pragma unroll
        for (int k = 0; k < 32; k += 8)
            tile[(y + k) * 33 + x] = S[(size_t)(s0 + y + k) * DIMD + c0 + x];
        __syncthreads();
#pragma unroll
        for (int k = 0; k < 32; k += 8)
            D[(size_t)(c0 + y + k) * NS + s0 + x] = tile[x * 33 + y + k];
    }
}

// ---------------- scan: 8 blocks/batch, tagged-data sync, fused final ----------------
// grid 256 = 32 batches x 8 e-slices; block 512 threads (8 waves), 1 block/CU.
// XCD-affinity: b = bid&31, j = bid>>5 (halved scan FETCH, round 9).
// Last step: every block gathers full r and writes its g-slice (k_final fused).
__global__ __launch_bounds__(512, 2) void k_scan(
    const __bf16* __restrict__ ctxdm,  // [b*256+s][512]
    const __bf16* __restrict__ ctxT,   // [b][c][s]
    const __bf16* __restrict__ wrmT,   // [c][d]
    const __bf16* __restrict__ wrrT,   // [c][d]
    const float* __restrict__ qmf,     // [t*32+b][512]
    const float* __restrict__ wms, const float* __restrict__ brm,
    const float* __restrict__ brr,
    const float* __restrict__ qh,      // [b][512]
    const __bf16* __restrict__ wrgT,   // [c][d]
    const __bf16* __restrict__ wqgT,   // [c][d]
    const float* __restrict__ brg, const float* __restrict__ bqg,
    u64* parts,                        // [b][8][256] tagged
    u64* rpub,                         // [b][512] tagged
    float* __restrict__ out) {         // [b][512] final g
    int bid = blockIdx.x;
    int b = bid & 31, j = bid >> 5;        // XCD-affinity mapping
    int tid = threadIdx.x, wave = tid >> 6, lane = tid & 63;
    int g = lane >> 3, i = lane & 7;       // s-subgroup, e-chunk

    __shared__ __bf16 sA[256 * SA_STR];    // 33.8 KB (ctxdm slice)
    __shared__ __bf16 sCT[64 * SCT_STR];   // 33.0 KB (ctxT slice)
    __shared__ float  sQ[NT * 64];         //  8 KB
    __shared__ float  sq[512];             // B1 gather sums
    __shared__ float  sp[256];             // exp values
    __shared__ float  s4[4];
    __shared__ float  sps[8 * 68];         // B1 per-wave partials (stride 68)
    __shared__ float  srm[64], sh[64];
    __shared__ float  sr4[4 * SR_STR];     // r in 4 padded chunks
    __shared__ float  sqh4[4 * SR_STR];    // qh in 4 padded chunks (final step)
    __shared__ float  smv[512];

    // ---- one-time staging ----
    for (int c = tid; c < 2048; c += 512) {            // sA: 256 rows x 64 e
        int row = c >> 3, c8 = c & 7;
        *(bf16x8*)(sA + row * SA_STR + c8 * 8) =
            *(const bf16x8*)(ctxdm + ((size_t)(b * NS + row)) * DIMD + j * 64 + c8 * 8);
    }
    for (int c = tid; c < 2048; c += 512) {            // sCT: 64 cols x 256 s
        int col = c >> 5, s8 = c & 31;
        *(bf16x8*)(sCT + col * SCT_STR + s8 * 8) =
            *(const bf16x8*)(ctxT + ((size_t)(b * DIMD) + j * 64 + col) * NS + s8 * 8);
    }
    for (int c = tid; c < NT * 64; c += 512) {         // sQ
        int tt = c >> 6, e = c & 63;
        sQ[c] = qmf[((size_t)tt * NB + b) * DIMD + j * 64 + e];
    }
    sqh4[(tid >> 7) * SR_STR + (tid & 127)] = qh[(size_t)b * DIMD + tid];
    // weight slice -> registers: thread (m,cl,q) owns d in [q*128,(q+1)*128)
    int m = tid >> 8, cl = (tid >> 2) & 63, q = tid & 3;
    const __bf16* wp = (m ? wrrT : wrmT) + ((size_t)(j * 64 + cl)) * DIMD + q * 128;
    bf16x8 wreg[16];
#pragma unroll
    for (int u = 0; u < 16; u++) wreg[u] = *(const bf16x8*)(wp + u * 8);

    float wm[8];
#pragma unroll
    for (int u = 0; u < 8; u++) wm[u] = wms[j * 64 + i * 8 + u];
    if (tid < 64) {
        srm[tid] = brm[j * 64 + tid];            // rm_0 slice (r0 = 0)
        sh[tid]  = tanh_fast(brr[j * 64 + tid]); // h_0 slice
    }
    __syncthreads();

    for (int t = 0; t < NT; t++) {
        unsigned tag = (unsigned)(t + 1);
        // ---- phase A: partial logits, published directly from the loop ----
        float rq[8];
#pragma unroll
        for (int u = 0; u < 8; u++) rq[u] = srm[i * 8 + u] + sQ[t * 64 + i * 8 + u];
#pragma unroll
        for (int k = 0; k < 4; k++) {
            int s = wave * 32 + k * 8 + g;
            bf16x8 cv = *(const bf16x8*)(sA + s * SA_STR + i * 8);
            float a = 0.f;
#pragma unroll
            for (int u = 0; u < 8; u++)
                a += tanh_fast((float)cv[u] + rq[u]) * wm[u];
            a += __shfl_xor(a, 1); a += __shfl_xor(a, 2); a += __shfl_xor(a, 4);
            if (i == 0) pub64(&parts[(b * 8 + j) * NS + s], a, tag);
        }

        // ---- phase B1: batched poll, softmax, weighted ctx sum -> r-slice ----
        {
            int s = tid >> 1, jh = (tid & 1) * 4;
            const u64* p0 = &parts[(b * 8 + jh + 0) * NS + s];
            const u64* p1 = &parts[(b * 8 + jh + 1) * NS + s];
            const u64* p2 = &parts[(b * 8 + jh + 2) * NS + s];
            const u64* p3 = &parts[(b * 8 + jh + 3) * NS + s];
            u64 v0, v1, v2, v3;
            for (;;) {
                v0 = __hip_atomic_load(p0, __ATOMIC_RELAXED, __HIP_MEMORY_SCOPE_AGENT);
                v1 = __hip_atomic_load(p1, __ATOMIC_RELAXED, __HIP_MEMORY_SCOPE_AGENT);
                v2 = __hip_atomic_load(p2, __ATOMIC_RELAXED, __HIP_MEMORY_SCOPE_AGENT);
                v3 = __hip_atomic_load(p3, __ATOMIC_RELAXED, __HIP_MEMORY_SCOPE_AGENT);
                if ((unsigned)v0 == tag && (unsigned)v1 == tag &&
                    (unsigned)v2 == tag && (unsigned)v3 == tag) break;
                __builtin_amdgcn_s_sleep(1);
            }
            sq[tid] = __uint_as_float((unsigned)(v0 >> 32)) + __uint_as_float((unsigned)(v1 >> 32))
                    + __uint_as_float((unsigned)(v2 >> 32)) + __uint_as_float((unsigned)(v3 >> 32));
        }
        __syncthreads();
        float ev = 0.f;
        if (tid < NS) { ev = __expf(sq[2 * tid] + sq[2 * tid + 1]); sp[tid] = ev; }
#pragma unroll
        for (int off = 32; off; off >>= 1) ev += __shfl_xor(ev, off);
        if (tid < NS && lane == 0) s4[wave] = ev;
        __syncthreads();
        float inv = 1.f / (s4[0] + s4[1] + s4[2] + s4[3]);
        {
            const __bf16* cp = sCT + lane * SCT_STR + wave * 32;
            const float* pp = sp + wave * 32;
            float a = 0.f;
#pragma unroll
            for (int k = 0; k < 32; k += 8) {
                bf16x8 v = *(const bf16x8*)(cp + k);
#pragma unroll
                for (int u = 0; u < 8; u++) a = fmaf(pp[k + u], (float)v[u], a);
            }
            sps[wave * 68 + lane] = a;
        }
        __syncthreads();
        if (tid < 64) {
            float a = 0.f;
#pragma unroll
            for (int w2 = 0; w2 < 8; w2++) a += sps[w2 * 68 + tid];
            float rv = a * inv + sh[tid];
            pub64(&rpub[b * DIMD + j * 64 + tid], rv, tag);
        }

        // ---- phase B2 / final: gather full r ----
        sr4[(tid >> 7) * SR_STR + (tid & 127)] = poll64(&rpub[b * DIMD + tid], tag);
        __syncthreads();
        if (t < NT - 1) {
            // register-weight matvec -> rm/h (block-local)
            const float* sv = sr4 + q * SR_STR;   // q-groups on distinct banks
            float a0 = 0.f, a1 = 0.f;
#pragma unroll
            for (int u = 0; u < 16; u += 2) {
                bf16x8 w0 = wreg[u], w1 = wreg[u + 1];
#pragma unroll
                for (int e = 0; e < 8; e++) {
                    a0 = fmaf(sv[u * 8 + e],     (float)w0[e], a0);
                    a1 = fmaf(sv[u * 8 + 8 + e], (float)w1[e], a1);
                }
            }
            smv[tid] = a0 + a1;
            __syncthreads();
            if (tid < 128) {
                int m2 = tid >> 6, cl3 = tid & 63;
                float a = smv[m2 * 256 + cl3 * 4] + smv[m2 * 256 + cl3 * 4 + 1]
                        + smv[m2 * 256 + cl3 * 4 + 2] + smv[m2 * 256 + cl3 * 4 + 3];
                int col = j * 64 + cl3;
                if (m2 == 0) srm[cl3] = a + brm[col];
                else         sh[cl3]  = tanh_fast(a + brr[col]);
            }
            __syncthreads();
        } else {
            // fused k_final: g[j-slice] = r@W_rg + qh@W_qg + brg + bqg
            const __bf16* wp2 = (m ? wqgT : wrgT) + ((size_t)(j * 64 + cl)) * DIMD + q * 128;
            const float* sv = (m ? sqh4 : sr4) + q * SR_STR;
            float a0 = 0.f, a1 = 0.f;
#pragma unroll
            for (int u = 0; u < 16; u += 2) {
                bf16x8 w0 = *(const bf16x8*)(wp2 + u * 8);
                bf16x8 w1 = *(const bf16x8*)(wp2 + u * 8 + 8);
#pragma unroll
                for (int e = 0; e < 8; e++) {
                    a0 = fmaf(sv[u * 8 + e],     (float)w0[e], a0);
                    a1 = fmaf(sv[u * 8 + 8 + e], (float)w1[e], a1);
                }
            }
            smv[tid] = a0 + a1;
            __syncthreads();
            if (tid < 64) {
                int col = j * 64 + tid;
                float a = brg[col] + bqg[col];
#pragma unroll
                for (int m2 = 0; m2 < 2; m2++)
#pragma unroll
                    for (int q2 = 0; q2 < 4; q2++)
                        a += smv[m2 * 256 + tid * 4 + q2];
                out[(size_t)b * DIMD + col] = a;
            }
        }
    }
}

// ---------------- host ----------------

extern "C" void kernel_launch(void* const* d_in, const int* in_sizes, int n_in,
                              void* d_out, int out_size, void* d_ws, size_t ws_size,
                              hipStream_t stream) {
    const float* ctx_in = (const float*)d_in[0];
    const float* q_in   = (const float*)d_in[1];
    const float* qh     = (const float*)d_in[2];
    const float* img    = (const float*)d_in[3];
    const float* W_fc1  = (const float*)d_in[4];
    const float* b_fc1  = (const float*)d_in[5];
    const float* W_fc2  = (const float*)d_in[6];
    const float* b_fc2  = (const float*)d_in[7];
    const float* W_dm   = (const float*)d_in[8];
    const float* b_dm   = (const float*)d_in[9];
    const float* W_rm   = (const float*)d_in[10];
    const float* b_rm   = (const float*)d_in[11];
    const float* W_qm   = (const float*)d_in[12];
    const float* b_qm   = (const float*)d_in[13];
    const float* W_rr   = (const float*)d_in[14];
    const float* b_rr   = (const float*)d_in[15];
    const float* W_rg   = (const float*)d_in[16];
    const float* b_rg   = (const float*)d_in[17];
    const float* W_qg   = (const float*)d_in[18];
    const float* b_qg   = (const float*)d_in[19];
    const float* W_ms   = (const float*)d_in[20];
    // d_in[21] = b_ms: unused (softmax shift-invariant)

    // workspace layout (38.78 MB main chain). RULE: x-region aliases acat ->
    // only WRITTEN after g1 consumed acat (round-8 NaN was a violation).
    char* w = (char*)d_ws;
    __bf16* acat  = (__bf16*)w;  w += (size_t)8192 * 1024 * 2;   // 16.78 MB, dead after g1
    __bf16* qp    = (__bf16*)w;  w += (size_t)1024 * 512 * 2;
    __bf16* wcatT = (__bf16*)w;  w += (size_t)512 * 1024 * 2;
    __bf16* wdmT  = (__bf16*)w;  w += (size_t)512 * 512 * 2;
    __bf16* wqmT  = (__bf16*)w;  w += (size_t)512 * 512 * 2;
    __bf16* wrmT  = (__bf16*)w;  w += (size_t)512 * 512 * 2;
    __bf16* wrrT  = (__bf16*)w;  w += (size_t)512 * 512 * 2;
    __bf16* wrgT  = (__bf16*)w;  w += (size_t)512 * 512 * 2;
    __bf16* wqgT  = (__bf16*)w;  w += (size_t)512 * 512 * 2;
    __bf16* ctxb  = (__bf16*)w;  w += (size_t)8192 * 512 * 2;
    __bf16* ctxdm = (__bf16*)w;  w += (size_t)8192 * 512 * 2;
    // sub-allocate dead acat region (written only after g1 consumed it)
    char* x = (char*)acat;
    __bf16* ctxT  = (__bf16*)x;  x += (size_t)NB * DIMD * NS * 2;  // 8.39 MB
    float*  qmf   = (float*)x;   x += (size_t)1024 * 512 * 4;      // 2.10 MB
    u64*    rpub  = (u64*)x;     x += (size_t)NB * DIMD * 8;       // 128 KB tagged
    u64*    parts = (u64*)x;     x += (size_t)NB * 8 * NS * 8;     // 512 KB tagged

    // 1. fused prep: acat + qp + all eight weight transposes
    k_prep_all<<<12288, 256, 0, stream>>>(ctx_in, img, q_in, W_fc1, W_fc2, W_dm,
                                          W_qm, W_rm, W_rr, W_rg, W_qg, acat, qp,
                                          wcatT, wdmT, wqmT, wrmT, wrrT, wrgT, wqgT);
    // 2. g1: ctx = acat @ W_cat^T + bfc1 + bfc2   (128-tile; consumes acat)
    k_gemm128<<<dim3(64, 4), 256, 0, stream>>>(acat, wcatT, b_fc1, b_fc2, ctxb, 8192, 512, 1024, 0);
    // 3. fused post-g1: g2 + qm GEMMs (128-tile) + ctxT transpose (acat dead)
    k_fused<<<4384, 256, 0, stream>>>(ctxb, wdmT, b_dm, ctxdm, qp, wqmT, b_qm, qmf, ctxT);
    // 4. scan + fused final: 256 blocks (8 per batch) x 512 threads
    k_scan<<<256, 512, 0, stream>>>(ctxdm, ctxT, wrmT, wrrT, qmf, W_ms,
                                    b_rm, b_rr, qh, wrgT, wqgT, b_rg, b_qg,
                                    parts, rpub, (float*)d_out);
}

// Round 14
// 432.597 us; speedup vs baseline: 1.2138x; 1.0022x over previous
//
#include <hip/hip_runtime.h>
#include <hip/hip_bf16.h>

// Problem dims (fixed by reference): D=512, B=32, S_c=256, S_q(T)=32
#define DIMD 512
#define NB   32
#define NS   256
#define NT   32
// LDS strides chosen for bank-conflict freedom
#define SCT_STR 258   // ctxT slice rows (bf16): 516B = 129 dw ≡ 1 mod 32
#define SR_STR  132   // r/qh chunks (fp32): q-groups on distinct banks

typedef __bf16 bf16x8 __attribute__((ext_vector_type(8)));
typedef float  f32x4  __attribute__((ext_vector_type(4)));
typedef unsigned long long u64;

__device__ __forceinline__ float tanh_fast(float x) {
    float e = __expf(2.f * x);
    return 1.f - 2.f / (e + 1.f);
}

// async global->LDS, 16B per lane; lds dest = wave-uniform base + lane*16
__device__ __forceinline__ void gl_lds16(const __bf16* g, __bf16* l) {
    __builtin_amdgcn_global_load_lds((const __attribute__((address_space(1))) void*)g,
                                     (__attribute__((address_space(3))) void*)l, 16, 0, 0);
}

// ---- tagged-data sync: {value,tag} in one 64-bit relaxed atomic (proven r10-13).
// Tags 1..NT never collide with the 0xAAAAAAAA workspace poison.
__device__ __forceinline__ void pub64(u64* p, float v, unsigned tag) {
    u64 pk = ((u64)__float_as_uint(v) << 32) | (u64)tag;
    __hip_atomic_store(p, pk, __ATOMIC_RELAXED, __HIP_MEMORY_SCOPE_AGENT);
}
__device__ __forceinline__ float poll64(const u64* p, unsigned tag) {
    u64 v = __hip_atomic_load(p, __ATOMIC_RELAXED, __HIP_MEMORY_SCOPE_AGENT);
    while ((unsigned)v != tag) {
        __builtin_amdgcn_s_sleep(1);
        v = __hip_atomic_load(p, __ATOMIC_RELAXED, __HIP_MEMORY_SCOPE_AGENT);
    }
    return __uint_as_float((unsigned)(v >> 32));
}

// ---------------- fused prep: acat + q cast + EIGHT weight transposes ----------------
__global__ void k_prep_all(const float* __restrict__ ctxin, const float* __restrict__ img,
                           const float* __restrict__ qin,
                           const float* __restrict__ Wfc1, const float* __restrict__ Wfc2,
                           const float* __restrict__ Wdm, const float* __restrict__ Wqm,
                           const float* __restrict__ Wrm, const float* __restrict__ Wrr,
                           const float* __restrict__ Wrg, const float* __restrict__ Wqg,
                           __bf16* __restrict__ acat, __bf16* __restrict__ qp,
                           __bf16* __restrict__ wcatT, __bf16* __restrict__ wdmT,
                           __bf16* __restrict__ wqmT, __bf16* __restrict__ wrmT,
                           __bf16* __restrict__ wrrT, __bf16* __restrict__ wrgT,
                           __bf16* __restrict__ wqgT) {
    int row = blockIdx.x;
    if (row < 8192) {
        int b = row >> 8, s = row & 255;
        const float* c  = ctxin + ((size_t)s * NB + b) * DIMD;
        const float* im = img   + ((size_t)s * NB + b) * DIMD;
        __bf16* o = acat + (size_t)row * 1024;
        for (int d = threadIdx.x; d < DIMD; d += 256) {
            o[d]       = (__bf16)c[d];
            o[512 + d] = (__bf16)im[d];
        }
    } else if (row < 10240) {
        int idx = (row - 8192) * 256 + threadIdx.x;   // 2048*256 = NT*NB*DIMD
        qp[idx] = (__bf16)qin[idx];
    } else {
        __shared__ float tile[32][33];
        int zz = (row - 10240) >> 8;       // matrix id 0..7
        int idx = (row - 10240) & 255;
        int bx = idx & 15, by = idx >> 4;
        int x = threadIdx.x & 31, y = threadIdx.x >> 5;   // 32 x 8
        const float* src = (zz == 0) ? Wfc1 : (zz == 1) ? Wfc2 : (zz == 2) ? Wdm
                         : (zz == 3) ? Wqm : (zz == 4) ? Wrm : (zz == 5) ? Wrr
                         : (zz == 6) ? Wrg : Wqg;
        __bf16* dst; int stride, off;
        if (zz < 2) { dst = wcatT; stride = 1024; off = zz * 512; }
        else {
            dst = (zz == 2) ? wdmT : (zz == 3) ? wqmT : (zz == 4) ? wrmT
                : (zz == 5) ? wrrT : (zz == 6) ? wrgT : wqgT;
            stride = 512; off = 0;
        }
        int c0 = bx * 32, r0 = by * 32;
#pragma unroll
        for (int k = 0; k < 32; k += 8)
            tile[y + k][x] = src[(size_t)(r0 + y + k) * DIMD + c0 + x];
        __syncthreads();
#pragma unroll
        for (int k = 0; k < 32; k += 8)
            dst[(size_t)(c0 + y + k) * stride + off + r0 + x] = (__bf16)tile[x][y + k];
    }
}

// ---------------- 128x128-tile GEMM body (round-3/13 proven) ----------------
__device__ __forceinline__ void gemm_tile128(const __bf16* __restrict__ A,
                                             const __bf16* __restrict__ BT,
                                             const float* __restrict__ bias1,
                                             const float* __restrict__ bias2,
                                             void* __restrict__ out, int N, int K,
                                             int m0, int n0, int out_f32,
                                             __bf16* As, __bf16* Bs) {
    int tid = threadIdx.x, wave = tid >> 6, lane = tid & 63;
    int wm_ = wave >> 1, wn = wave & 1;
    int lr = lane & 15, lq = lane >> 4;

    f32x4 acc[4][4];
#pragma unroll
    for (int i = 0; i < 4; i++)
#pragma unroll
        for (int j = 0; j < 4; j++) acc[i][j] = (f32x4){0.f, 0.f, 0.f, 0.f};

    int g0 = (wave * 2 + 0) * 64 + lane;
    int g1 = (wave * 2 + 1) * 64 + lane;
    int r0_ = g0 >> 2, c0_ = g0 & 3;
    int r1_ = g1 >> 2, c1_ = g1 & 3;
    __bf16* la0 = As + (wave * 2 + 0) * 512;
    __bf16* la1 = As + (wave * 2 + 1) * 512;
    __bf16* lb0 = Bs + (wave * 2 + 0) * 512;
    __bf16* lb1 = Bs + (wave * 2 + 1) * 512;

    for (int kk = 0; kk < K; kk += 32) {
        gl_lds16(A  + (size_t)(m0 + r0_) * K + kk + c0_ * 8, la0);
        gl_lds16(A  + (size_t)(m0 + r1_) * K + kk + c1_ * 8, la1);
        gl_lds16(BT + (size_t)(n0 + r0_) * K + kk + c0_ * 8, lb0);
        gl_lds16(BT + (size_t)(n0 + r1_) * K + kk + c1_ * 8, lb1);
        __syncthreads();
        bf16x8 af[4], bfv[4];
#pragma unroll
        for (int i = 0; i < 4; i++)
            af[i] = *(const bf16x8*)(As + (wm_ * 64 + i * 16 + lr) * 32 + lq * 8);
#pragma unroll
        for (int j = 0; j < 4; j++)
            bfv[j] = *(const bf16x8*)(Bs + (wn * 64 + j * 16 + lr) * 32 + lq * 8);
#pragma unroll
        for (int i = 0; i < 4; i++)
#pragma unroll
            for (int j = 0; j < 4; j++)
                acc[i][j] = __builtin_amdgcn_mfma_f32_16x16x32_bf16(af[i], bfv[j], acc[i][j], 0, 0, 0);
        __syncthreads();
    }

#pragma unroll
    for (int i = 0; i < 4; i++)
#pragma unroll
        for (int j = 0; j < 4; j++) {
            int col = n0 + wn * 64 + j * 16 + lr;
            float bs = (bias1 ? bias1[col] : 0.f) + (bias2 ? bias2[col] : 0.f);
#pragma unroll
            for (int r = 0; r < 4; r++) {
                int row = m0 + wm_ * 64 + i * 16 + lq * 4 + r;   // verified C/D layout
                float v = acc[i][j][r] + bs;
                if (out_f32) ((float*)out)[(size_t)row * N + col] = v;
                else         ((__bf16*)out)[(size_t)row * N + col] = (__bf16)v;
            }
        }
}

__global__ void k_gemm128(const __bf16* __restrict__ A, const __bf16* __restrict__ BT,
                          const float* __restrict__ bias1, const float* __restrict__ bias2,
                          void* __restrict__ out, int M, int N, int K, int out_f32) {
    __shared__ __bf16 As[128 * 32];
    __shared__ __bf16 Bs[128 * 32];
    gemm_tile128(A, BT, bias1, bias2, out, N, K, blockIdx.x * 128, blockIdx.y * 128, out_f32, As, Bs);
}

// fused post-g1: blocks 0..255 g2; 256..287 qm GEMM; 288..4383 ctxT transpose
__global__ void k_fused(const __bf16* __restrict__ ctxb, const __bf16* __restrict__ wdmT,
                        const float* __restrict__ bdm, __bf16* __restrict__ ctxdm,
                        const __bf16* __restrict__ qp, const __bf16* __restrict__ wqmT,
                        const float* __restrict__ bqm, float* __restrict__ qmf,
                        __bf16* __restrict__ ctxT) {
    __shared__ __bf16 As[128 * 32];
    __shared__ __bf16 Bs[128 * 32];
    int bid = blockIdx.x;
    if (bid < 256) {
        gemm_tile128(ctxb, wdmT, bdm, nullptr, ctxdm, 512, 512,
                     (bid & 63) * 128, (bid >> 6) * 128, 0, As, Bs);
    } else if (bid < 288) {
        int b2 = bid - 256;
        gemm_tile128(qp, wqmT, bqm, nullptr, qmf, 512, 512,
                     (b2 & 7) * 128, (b2 >> 3) * 128, 1, As, Bs);
    } else {
        int b3 = bid - 288;
        int z = b3 >> 7, rest = b3 & 127;
        int c0 = (rest & 15) * 32, s0 = (rest >> 4) * 32;
        __bf16* tile = As;   // reuse gemm LDS as [32][33] bf16 tile
        int x = threadIdx.x & 31, y = threadIdx.x >> 5;   // 32 x 8
        const __bf16* S = ctxb + (size_t)z * NS * DIMD;
        __bf16* D = ctxT + (size_t)z * DIMD * NS;
#pragma unroll
        for (int k = 0; k < 32; k += 8)
            tile[(y + k) * 33 + x] = S[(size_t)(s0 + y + k) * DIMD + c0 + x];
        __syncthreads();
#pragma unroll
        for (int k = 0; k < 32; k += 8)
            D[(size_t)(c0 + y + k) * NS + s0 + x] = tile[x * 33 + y + k];
    }
}

// ---------------- scan: s-sliced logits + atomic d-reduce (round-14 comm plan) ----------------
// grid 256 = 32 batches x 8 slices; block 512 thr; b = bid&31, j = bid>>5 (XCD affinity).
// Block (b,j) owns: s-rows [j*32,(j+1)*32) for COMPLETE logits (needs full rm),
// cols [j*64,(j+1)*64) for r. Exchange A: 32 final logits/block (poll 256).
// Exchange B: fp32 atomicAdd of rm/rr d-slice partials into pre-zeroed per-step
// buffers + tagged token after vmcnt drain; consumers poll 8 tokens then bulk-read.
__global__ __launch_bounds__(512, 2) void k_scan(
    const __bf16* __restrict__ ctxdm,  // [b*256+s][512]
    const __bf16* __restrict__ ctxT,   // [b][c][s]
    const __bf16* __restrict__ wrmT,   // [c][d] = W_rm[d][c]
    const __bf16* __restrict__ wrrT,   // [c][d]
    const float* __restrict__ qmf,     // [t*32+b][512]
    const float* __restrict__ wms, const float* __restrict__ brm,
    const float* __restrict__ brr,
    const float* __restrict__ qh,      // [b][512]
    const __bf16* __restrict__ wrgT,   // [c][d]
    const __bf16* __restrict__ wqgT,   // [c][d]
    const float* __restrict__ brg, const float* __restrict__ bqg,
    u64* parts,                        // [b][256] tagged complete logits
    u64* rpub,                         // [b][512] tagged (final step only)
    u64* tok,                          // [b][8] tagged tokens
    float* rmsum,                      // [31][b][512] fp32, pre-zeroed
    float* rrsum,                      // [31][b][512] fp32, pre-zeroed
    float* __restrict__ out) {         // [b][512] final g
    int bid = blockIdx.x;
    int b = bid & 31, j = bid >> 5;
    int tid = threadIdx.x, wave = tid >> 6, lane = tid & 63;

    __shared__ __bf16 sA[32 * 512];        // 32 KB: ctxdm rows [j*32..) x all 512 e
    __shared__ __bf16 sCT[64 * SCT_STR];   // 33 KB: ctxT own cols x all 256 s
    __shared__ float  srm[DIMD];           // full rm
    __shared__ float  sQt[DIMD];           // qm for current step
    __shared__ float  sp[NS];              // softmax weights
    __shared__ float  s4[4];
    __shared__ float  sps[8 * 68];
    __shared__ float  sh[64], srl[64];     // own h, own r-slice
    __shared__ float  sr4[4 * SR_STR];     // full r (final step)
    __shared__ float  sqh4[4 * SR_STR];    // qh (final step)
    __shared__ float  smv[512];

    // ---- one-time staging ----
    for (int c = tid; c < 2048; c += 512) {            // sA: 32 rows x 512 e
        int row = c >> 6, c8 = c & 63;
        *(bf16x8*)(sA + row * 512 + c8 * 8) =
            *(const bf16x8*)(ctxdm + ((size_t)(b * NS + j * 32 + row)) * DIMD + c8 * 8);
    }
    for (int c = tid; c < 2048; c += 512) {            // sCT: 64 cols x 256 s
        int col = c >> 5, s8 = c & 31;
        *(bf16x8*)(sCT + col * SCT_STR + s8 * 8) =
            *(const bf16x8*)(ctxT + ((size_t)(b * DIMD) + j * 64 + col) * NS + s8 * 8);
    }
    sqh4[(tid >> 7) * SR_STR + (tid & 127)] = qh[(size_t)b * DIMD + tid];
    // weight rows -> regs: thread e=tid holds W_rm[j-slice d][e], W_rr[j-slice d][e]
    const __bf16* wpm = wrmT + (size_t)tid * DIMD + j * 64;
    const __bf16* wpr = wrrT + (size_t)tid * DIMD + j * 64;
    bf16x8 wregm[8], wregr[8];
#pragma unroll
    for (int u = 0; u < 8; u++) { wregm[u] = *(const bf16x8*)(wpm + u * 8);
                                  wregr[u] = *(const bf16x8*)(wpr + u * 8); }
    float wm[8];
#pragma unroll
    for (int u = 0; u < 8; u++) wm[u] = wms[lane * 8 + u];

    srm[tid] = brm[tid];                       // rm_0 = b_rm (r0 = 0)
    if (tid < 64) sh[tid] = tanh_fast(brr[j * 64 + tid]);
    sQt[tid] = qmf[(size_t)b * DIMD + tid];    // t = 0
    __syncthreads();

    for (int t = 0; t < NT; t++) {
        unsigned tag = (unsigned)(t + 1);
        // ---- phase A: COMPLETE logits for own 32 s-rows (full-e dot) ----
        float rq[8];
#pragma unroll
        for (int u = 0; u < 8; u++) rq[u] = srm[lane * 8 + u] + sQt[lane * 8 + u];
#pragma unroll
        for (int k = 0; k < 4; k++) {
            int row = wave * 4 + k;
            bf16x8 cv = *(const bf16x8*)(sA + row * 512 + lane * 8);
            float a = 0.f;
#pragma unroll
            for (int u = 0; u < 8; u++)
                a += tanh_fast((float)cv[u] + rq[u]) * wm[u];
#pragma unroll
            for (int off = 32; off; off >>= 1) a += __shfl_xor(a, off);
            if (lane == 0) pub64(&parts[b * NS + j * 32 + row], a, tag);
        }

        // ---- phase B1: poll 256 final logits, softmax, weighted ctx -> r-slice ----
        float ev = 0.f;
        if (tid < NS) { float lg = poll64(&parts[b * NS + tid], tag);
                        ev = __expf(lg); sp[tid] = ev; }
#pragma unroll
        for (int off = 32; off; off >>= 1) ev += __shfl_xor(ev, off);
        if (tid < NS && lane == 0) s4[wave] = ev;
        __syncthreads();
        float inv = 1.f / (s4[0] + s4[1] + s4[2] + s4[3]);
        {
            const __bf16* cp = sCT + lane * SCT_STR + wave * 32;
            const float* pp = sp + wave * 32;
            float a = 0.f;
#pragma unroll
            for (int k = 0; k < 32; k += 8) {
                bf16x8 v = *(const bf16x8*)(cp + k);
#pragma unroll
                for (int u = 0; u < 8; u++) a = fmaf(pp[k + u], (float)v[u], a);
            }
            sps[wave * 68 + lane] = a;
        }
        __syncthreads();
        if (tid < 64) {
            float a = 0.f;
#pragma unroll
            for (int w2 = 0; w2 < 8; w2++) a += sps[w2 * 68 + tid];
            float rv = a * inv + sh[tid];
            srl[tid] = rv;
            if (t == NT - 1) pub64(&rpub[b * DIMD + j * 64 + tid], rv, tag);
        }
        __syncthreads();

        if (t < NT - 1) {
            // ---- phase B2: d-slice partials of rm/rr for e=tid, atomicAdd + token ----
            float am = 0.f, ar = 0.f;
#pragma unroll
            for (int u = 0; u < 8; u++) {
                bf16x8 w0 = wregm[u], w1 = wregr[u];
#pragma unroll
                for (int e2 = 0; e2 < 8; e2++) {
                    float rv = srl[u * 8 + e2];           // broadcast read
                    am = fmaf(rv, (float)w0[e2], am);
                    ar = fmaf(rv, (float)w1[e2], ar);
                }
            }
            __hip_atomic_fetch_add(&rmsum[((size_t)t * NB + b) * DIMD + tid], am,
                                   __ATOMIC_RELAXED, __HIP_MEMORY_SCOPE_AGENT);
            __hip_atomic_fetch_add(&rrsum[((size_t)t * NB + b) * DIMD + tid], ar,
                                   __ATOMIC_RELAXED, __HIP_MEMORY_SCOPE_AGENT);
            __syncthreads();                   // drains vmcnt per wave
            if (tid == 0) {
                __atomic_signal_fence(__ATOMIC_SEQ_CST);
                __builtin_amdgcn_s_waitcnt(0x0F70);   // vmcnt(0) belt-and-suspenders
                __atomic_signal_fence(__ATOMIC_SEQ_CST);
                pub64(&tok[b * 8 + j], 0.f, tag);
            }
            if (tid < 8) poll64(&tok[b * 8 + tid], tag);
            __syncthreads();
            // gather assembled sums; prep next step's state
            srm[tid] = brm[tid] + __hip_atomic_load(&rmsum[((size_t)t * NB + b) * DIMD + tid],
                                                    __ATOMIC_RELAXED, __HIP_MEMORY_SCOPE_AGENT);
            if (tid < 64)
                sh[tid] = tanh_fast(brr[j * 64 + tid] +
                          __hip_atomic_load(&rrsum[((size_t)t * NB + b) * DIMD + j * 64 + tid],
                                            __ATOMIC_RELAXED, __HIP_MEMORY_SCOPE_AGENT));
            sQt[tid] = qmf[((size_t)(t + 1) * NB + b) * DIMD + tid];
            __syncthreads();
        } else {
            // ---- fused final: g[own cols] = r@W_rg + qh@W_qg + brg + bqg ----
            sr4[(tid >> 7) * SR_STR + (tid & 127)] = poll64(&rpub[b * DIMD + tid], tag);
            __syncthreads();
            int m = tid >> 8, cl = (tid >> 2) & 63, q = tid & 3;
            const __bf16* wp2 = (m ? wqgT : wrgT) + ((size_t)(j * 64 + cl)) * DIMD + q * 128;
            const float* sv = (m ? sqh4 : sr4) + q * SR_STR;
            float a0 = 0.f, a1 = 0.f;
#pragma unroll
            for (int u = 0; u < 16; u += 2) {
                bf16x8 w0 = *(const bf16x8*)(wp2 + u * 8);
                bf16x8 w1 = *(const bf16x8*)(wp2 + u * 8 + 8);
#pragma unroll
                for (int e2 = 0; e2 < 8; e2++) {
                    a0 = fmaf(sv[u * 8 + e2],     (float)w0[e2], a0);
                    a1 = fmaf(sv[u * 8 + 8 + e2], (float)w1[e2], a1);
                }
            }
            smv[tid] = a0 + a1;
            __syncthreads();
            if (tid < 64) {
                int col = j * 64 + tid;
                float a = brg[col] + bqg[col];
#pragma unroll
                for (int m2 = 0; m2 < 2; m2++)
#pragma unroll
                    for (int q2 = 0; q2 < 4; q2++)
                        a += smv[m2 * 256 + tid * 4 + q2];
                out[(size_t)b * DIMD + col] = a;
            }
        }
    }
}

// ---------------- host ----------------

extern "C" void kernel_launch(void* const* d_in, const int* in_sizes, int n_in,
                              void* d_out, int out_size, void* d_ws, size_t ws_size,
                              hipStream_t stream) {
    const float* ctx_in = (const float*)d_in[0];
    const float* q_in   = (const float*)d_in[1];
    const float* qh     = (const float*)d_in[2];
    const float* img    = (const float*)d_in[3];
    const float* W_fc1  = (const float*)d_in[4];
    const float* b_fc1  = (const float*)d_in[5];
    const float* W_fc2  = (const float*)d_in[6];
    const float* b_fc2  = (const float*)d_in[7];
    const float* W_dm   = (const float*)d_in[8];
    const float* b_dm   = (const float*)d_in[9];
    const float* W_rm   = (const float*)d_in[10];
    const float* b_rm   = (const float*)d_in[11];
    const float* W_qm   = (const float*)d_in[12];
    const float* b_qm   = (const float*)d_in[13];
    const float* W_rr   = (const float*)d_in[14];
    const float* b_rr   = (const float*)d_in[15];
    const float* W_rg   = (const float*)d_in[16];
    const float* b_rg   = (const float*)d_in[17];
    const float* W_qg   = (const float*)d_in[18];
    const float* b_qg   = (const float*)d_in[19];
    const float* W_ms   = (const float*)d_in[20];
    // d_in[21] = b_ms: unused (softmax shift-invariant)

    // workspace layout. RULE: x-region aliases acat -> only WRITTEN after g1
    // consumed acat (round-8 NaN was a violation).
    char* w = (char*)d_ws;
    __bf16* acat  = (__bf16*)w;  w += (size_t)8192 * 1024 * 2;   // 16.78 MB, dead after g1
    __bf16* qp    = (__bf16*)w;  w += (size_t)1024 * 512 * 2;
    __bf16* wcatT = (__bf16*)w;  w += (size_t)512 * 1024 * 2;
    __bf16* wdmT  = (__bf16*)w;  w += (size_t)512 * 512 * 2;
    __bf16* wqmT  = (__bf16*)w;  w += (size_t)512 * 512 * 2;
    __bf16* wrmT  = (__bf16*)w;  w += (size_t)512 * 512 * 2;
    __bf16* wrrT  = (__bf16*)w;  w += (size_t)512 * 512 * 2;
    __bf16* wrgT  = (__bf16*)w;  w += (size_t)512 * 512 * 2;
    __bf16* wqgT  = (__bf16*)w;  w += (size_t)512 * 512 * 2;
    __bf16* ctxb  = (__bf16*)w;  w += (size_t)8192 * 512 * 2;
    __bf16* ctxdm = (__bf16*)w;  w += (size_t)8192 * 512 * 2;
    // sub-allocate dead acat region (written only after g1 consumed it)
    char* x = (char*)acat;
    __bf16* ctxT  = (__bf16*)x;  x += (size_t)NB * DIMD * NS * 2;       // 8.39 MB
    float*  qmf   = (float*)x;   x += (size_t)1024 * 512 * 4;           // 2.10 MB
    u64*    parts = (u64*)x;     x += (size_t)NB * NS * 8;              //  64 KB
    u64*    rpub  = (u64*)x;     x += (size_t)NB * DIMD * 8;            // 128 KB
    u64*    tok   = (u64*)x;     x += (size_t)NB * 8 * 8;               //   2 KB
    float*  rmsum = (float*)x;   x += (size_t)(NT - 1) * NB * DIMD * 4; // 2.03 MB
    float*  rrsum = (float*)x;   x += (size_t)(NT - 1) * NB * DIMD * 4; // 2.03 MB

    // 1. fused prep: acat + qp + all eight weight transposes
    k_prep_all<<<12288, 256, 0, stream>>>(ctx_in, img, q_in, W_fc1, W_fc2, W_dm,
                                          W_qm, W_rm, W_rr, W_rg, W_qg, acat, qp,
                                          wcatT, wdmT, wqmT, wrmT, wrrT, wrgT, wqgT);
    // 2. g1: ctx = acat @ W_cat^T + bfc1 + bfc2   (128-tile; consumes acat)
    k_gemm128<<<dim3(64, 4), 256, 0, stream>>>(acat, wcatT, b_fc1, b_fc2, ctxb, 8192, 512, 1024, 0);
    // 3. fused post-g1: g2 + qm GEMMs (128-tile) + ctxT transpose (acat dead)
    k_fused<<<4384, 256, 0, stream>>>(ctxb, wdmT, b_dm, ctxdm, qp, wqmT, b_qm, qmf, ctxT);
    // zero the atomic accumulation buffers (stream-ordered after g1/fused;
    // kernel-boundary L2 flush makes zeros visible to CP atomics)
    hipMemsetAsync(rmsum, 0, (size_t)2 * (NT - 1) * NB * DIMD * 4, stream);
    // 4. scan + fused final
    k_scan<<<256, 512, 0, stream>>>(ctxdm, ctxT, wrmT, wrrT, qmf, W_ms,
                                    b_rm, b_rr, qh, wrgT, wqgT, b_rg, b_qg,
                                    parts, rpub, tok, rmsum, rrsum, (float*)d_out);
}

// Round 15
// 422.581 us; speedup vs baseline: 1.2426x; 1.0237x over previous
//
#include <hip/hip_runtime.h>
#include <hip/hip_bf16.h>

// Problem dims (fixed by reference): D=512, B=32, S_c=256, S_q(T)=32
#define DIMD 512
#define NB   32
#define NS   256
#define NT   32
// LDS strides chosen for bank-conflict freedom (dword-stride ≡ 1/2 mod 32)
#define SA_STR  66    // ctxdm slice rows (bf16): 132B = 33 dw ≡ 1
#define SCT_STR 258   // ctxT slice rows (bf16): 516B = 129 dw ≡ 1
#define SR_STR  132   // r/qh chunks (fp32): q-groups on distinct banks

typedef __bf16 bf16x8 __attribute__((ext_vector_type(8)));
typedef float  f32x4  __attribute__((ext_vector_type(4)));
typedef unsigned long long u64;

__device__ __forceinline__ float tanh_fast(float x) {
    float e = __expf(2.f * x);
    return 1.f - 2.f / (e + 1.f);
}

// async global->LDS, 16B per lane; lds dest = wave-uniform base + lane*16
__device__ __forceinline__ void gl_lds16(const __bf16* g, __bf16* l) {
    __builtin_amdgcn_global_load_lds((const __attribute__((address_space(1))) void*)g,
                                     (__attribute__((address_space(3))) void*)l, 16, 0, 0);
}

// ---- tagged-data sync: {value,tag} in one 64-bit relaxed atomic (proven r10-14).
// Tags 1..NT never collide with the 0xAAAAAAAA workspace poison.
__device__ __forceinline__ void pub64(u64* p, float v, unsigned tag) {
    u64 pk = ((u64)__float_as_uint(v) << 32) | (u64)tag;
    __hip_atomic_store(p, pk, __ATOMIC_RELAXED, __HIP_MEMORY_SCOPE_AGENT);
}
__device__ __forceinline__ float poll64(const u64* p, unsigned tag) {
    u64 v = __hip_atomic_load(p, __ATOMIC_RELAXED, __HIP_MEMORY_SCOPE_AGENT);
    while ((unsigned)v != tag) {
        __builtin_amdgcn_s_sleep(1);
        v = __hip_atomic_load(p, __ATOMIC_RELAXED, __HIP_MEMORY_SCOPE_AGENT);
    }
    return __uint_as_float((unsigned)(v >> 32));
}

// ---------------- fused prep: acat + q cast + EIGHT weight transposes ----------------
__global__ void k_prep_all(const float* __restrict__ ctxin, const float* __restrict__ img,
                           const float* __restrict__ qin,
                           const float* __restrict__ Wfc1, const float* __restrict__ Wfc2,
                           const float* __restrict__ Wdm, const float* __restrict__ Wqm,
                           const float* __restrict__ Wrm, const float* __restrict__ Wrr,
                           const float* __restrict__ Wrg, const float* __restrict__ Wqg,
                           __bf16* __restrict__ acat, __bf16* __restrict__ qp,
                           __bf16* __restrict__ wcatT, __bf16* __restrict__ wdmT,
                           __bf16* __restrict__ wqmT, __bf16* __restrict__ wrmT,
                           __bf16* __restrict__ wrrT, __bf16* __restrict__ wrgT,
                           __bf16* __restrict__ wqgT) {
    int row = blockIdx.x;
    if (row < 8192) {
        int b = row >> 8, s = row & 255;
        const float* c  = ctxin + ((size_t)s * NB + b) * DIMD;
        const float* im = img   + ((size_t)s * NB + b) * DIMD;
        __bf16* o = acat + (size_t)row * 1024;
        for (int d = threadIdx.x; d < DIMD; d += 256) {
            o[d]       = (__bf16)c[d];
            o[512 + d] = (__bf16)im[d];
        }
    } else if (row < 10240) {
        int idx = (row - 8192) * 256 + threadIdx.x;   // 2048*256 = NT*NB*DIMD
        qp[idx] = (__bf16)qin[idx];
    } else {
        __shared__ float tile[32][33];
        int zz = (row - 10240) >> 8;       // matrix id 0..7
        int idx = (row - 10240) & 255;
        int bx = idx & 15, by = idx >> 4;
        int x = threadIdx.x & 31, y = threadIdx.x >> 5;   // 32 x 8
        const float* src = (zz == 0) ? Wfc1 : (zz == 1) ? Wfc2 : (zz == 2) ? Wdm
                         : (zz == 3) ? Wqm : (zz == 4) ? Wrm : (zz == 5) ? Wrr
                         : (zz == 6) ? Wrg : Wqg;
        __bf16* dst; int stride, off;
        if (zz < 2) { dst = wcatT; stride = 1024; off = zz * 512; }
        else {
            dst = (zz == 2) ? wdmT : (zz == 3) ? wqmT : (zz == 4) ? wrmT
                : (zz == 5) ? wrrT : (zz == 6) ? wrgT : wqgT;
            stride = 512; off = 0;
        }
        int c0 = bx * 32, r0 = by * 32;
#pragma unroll
        for (int k = 0; k < 32; k += 8)
            tile[y + k][x] = src[(size_t)(r0 + y + k) * DIMD + c0 + x];
        __syncthreads();
#pragma unroll
        for (int k = 0; k < 32; k += 8)
            dst[(size_t)(c0 + y + k) * stride + off + r0 + x] = (__bf16)tile[x][y + k];
    }
}

// ---------------- 128x64-tile GEMM body, BK=64 (round-15: 2 blocks/CU so the
// vmcnt(0)+barrier drain of one block overlaps the co-resident block's MFMA
// — the m114/m97 mechanism the 1-block/CU 128x128 tile couldn't use) ----------------
// 256 thr = 4 waves; wave tile 64x32 (4x2 of 16x16x32 MFMA); LDS 24 KB.
__device__ __forceinline__ void gemm_tile(const __bf16* __restrict__ A,
                                          const __bf16* __restrict__ BT,
                                          const float* __restrict__ bias1,
                                          const float* __restrict__ bias2,
                                          void* __restrict__ out, int N, int K,
                                          int m0, int n0, int out_f32,
                                          __bf16* As, __bf16* Bs) {
    int tid = threadIdx.x, wave = tid >> 6, lane = tid & 63;
    int wm_ = wave >> 1, wn = wave & 1;
    int lr = lane & 15, lq = lane >> 4;
    int lrow = lane >> 3, lcol8 = (lane & 7) * 8;   // staging: 8 rows x 64 k per chunk

    f32x4 acc[4][2];
#pragma unroll
    for (int i = 0; i < 4; i++)
#pragma unroll
        for (int j = 0; j < 2; j++) acc[i][j] = (f32x4){0.f, 0.f, 0.f, 0.f};

    for (int kk = 0; kk < K; kk += 64) {
        // A: 16 chunks (4/wave), rows [g*8,(g+1)*8), LDS row-major stride 64
#pragma unroll
        for (int i = 0; i < 4; i++) {
            int g = wave * 4 + i;
            gl_lds16(A + (size_t)(m0 + g * 8 + lrow) * K + kk + lcol8, As + g * 512);
        }
        // B: 8 chunks (2/wave)
#pragma unroll
        for (int i = 0; i < 2; i++) {
            int g = wave * 2 + i;
            gl_lds16(BT + (size_t)(n0 + g * 8 + lrow) * K + kk + lcol8, Bs + g * 512);
        }
        __syncthreads();
#pragma unroll
        for (int k2 = 0; k2 < 64; k2 += 32) {
            bf16x8 af[4], bfv[2];
#pragma unroll
            for (int i = 0; i < 4; i++)
                af[i] = *(const bf16x8*)(As + (wm_ * 64 + i * 16 + lr) * 64 + k2 + lq * 8);
#pragma unroll
            for (int j = 0; j < 2; j++)
                bfv[j] = *(const bf16x8*)(Bs + (wn * 32 + j * 16 + lr) * 64 + k2 + lq * 8);
#pragma unroll
            for (int i = 0; i < 4; i++)
#pragma unroll
                for (int j = 0; j < 2; j++)
                    acc[i][j] = __builtin_amdgcn_mfma_f32_16x16x32_bf16(af[i], bfv[j], acc[i][j], 0, 0, 0);
        }
        __syncthreads();
    }

#pragma unroll
    for (int i = 0; i < 4; i++)
#pragma unroll
        for (int j = 0; j < 2; j++) {
            int col = n0 + wn * 32 + j * 16 + lr;
            float bs = (bias1 ? bias1[col] : 0.f) + (bias2 ? bias2[col] : 0.f);
#pragma unroll
            for (int r = 0; r < 4; r++) {
                int row = m0 + wm_ * 64 + i * 16 + lq * 4 + r;   // verified C/D layout
                float v = acc[i][j][r] + bs;
                if (out_f32) ((float*)out)[(size_t)row * N + col] = v;
                else         ((__bf16*)out)[(size_t)row * N + col] = (__bf16)v;
            }
        }
}

// g1: ctx = acat @ W_cat^T + bfc1 + bfc2  (grid 64 x 8 = 512 blocks, 2/CU)
__global__ void k_gemm(const __bf16* __restrict__ A, const __bf16* __restrict__ BT,
                       const float* __restrict__ bias1, const float* __restrict__ bias2,
                       void* __restrict__ out, int M, int N, int K, int out_f32) {
    __shared__ __bf16 As[128 * 64];
    __shared__ __bf16 Bs[64 * 64];
    gemm_tile(A, BT, bias1, bias2, out, N, K, blockIdx.x * 128, blockIdx.y * 64, out_f32, As, Bs);
}

// fused post-g1: blocks 0..511 g2; 512..575 qm GEMM; 576..4671 ctxT transpose
__global__ void k_fused(const __bf16* __restrict__ ctxb, const __bf16* __restrict__ wdmT,
                        const float* __restrict__ bdm, __bf16* __restrict__ ctxdm,
                        const __bf16* __restrict__ qp, const __bf16* __restrict__ wqmT,
                        const float* __restrict__ bqm, float* __restrict__ qmf,
                        __bf16* __restrict__ ctxT) {
    __shared__ __bf16 As[128 * 64];
    __shared__ __bf16 Bs[64 * 64];
    int bid = blockIdx.x;
    if (bid < 512) {
        gemm_tile(ctxb, wdmT, bdm, nullptr, ctxdm, 512, 512,
                  (bid & 63) * 128, (bid >> 6) * 64, 0, As, Bs);
    } else if (bid < 576) {
        int b2 = bid - 512;
        gemm_tile(qp, wqmT, bqm, nullptr, qmf, 512, 512,
                  (b2 & 7) * 128, (b2 >> 3) * 64, 1, As, Bs);
    } else {
        int b3 = bid - 576;
        int z = b3 >> 7, rest = b3 & 127;
        int c0 = (rest & 15) * 32, s0 = (rest >> 4) * 32;
        __bf16* tile = As;   // reuse gemm LDS as [32][33] bf16 tile
        int x = threadIdx.x & 31, y = threadIdx.x >> 5;   // 32 x 8
        const __bf16* S = ctxb + (size_t)z * NS * DIMD;
        __bf16* D = ctxT + (size_t)z * DIMD * NS;
#pragma unroll
        for (int k = 0; k < 32; k += 8)
            tile[(y + k) * 33 + x] = S[(size_t)(s0 + y + k) * DIMD + c0 + x];
        __syncthreads();
#pragma unroll
        for (int k = 0; k < 32; k += 8)
            D[(size_t)(c0 + y + k) * NS + s0 + x] = tile[x * 33 + y + k];
    }
}

// ---------------- scan: round-13 structure (best measured: 281 us) ----------------
// grid 256 = 32 batches x 8 e-slices; block 512 threads (8 waves), 1 block/CU.
// XCD-affinity: b = bid&31, j = bid>>5. Tagged-data sync, fused final step.
__global__ __launch_bounds__(512, 2) void k_scan(
    const __bf16* __restrict__ ctxdm,  // [b*256+s][512]
    const __bf16* __restrict__ ctxT,   // [b][c][s]
    const __bf16* __restrict__ wrmT,   // [c][d]
    const __bf16* __restrict__ wrrT,   // [c][d]
    const float* __restrict__ qmf,     // [t*32+b][512]
    const float* __restrict__ wms, const float* __restrict__ brm,
    const float* __restrict__ brr,
    const float* __restrict__ qh,      // [b][512]
    const __bf16* __restrict__ wrgT,   // [c][d]
    const __bf16* __restrict__ wqgT,   // [c][d]
    const float* __restrict__ brg, const float* __restrict__ bqg,
    u64* parts,                        // [b][8][256] tagged
    u64* rpub,                         // [b][512] tagged
    float* __restrict__ out) {         // [b][512] final g
    int bid = blockIdx.x;
    int b = bid & 31, j = bid >> 5;        // XCD-affinity mapping
    int tid = threadIdx.x, wave = tid >> 6, lane = tid & 63;
    int g = lane >> 3, i = lane & 7;       // s-subgroup, e-chunk

    __shared__ __bf16 sA[256 * SA_STR];    // 33.8 KB (ctxdm slice)
    __shared__ __bf16 sCT[64 * SCT_STR];   // 33.0 KB (ctxT slice)
    __shared__ float  sQ[NT * 64];         //  8 KB
    __shared__ float  sq[512];             // B1 gather sums
    __shared__ float  sp[256];             // exp values
    __shared__ float  s4[4];
    __shared__ float  sps[8 * 68];         // B1 per-wave partials (stride 68)
    __shared__ float  srm[64], sh[64];
    __shared__ float  sr4[4 * SR_STR];     // r in 4 padded chunks
    __shared__ float  sqh4[4 * SR_STR];    // qh in 4 padded chunks (final step)
    __shared__ float  smv[512];

    // ---- one-time staging ----
    for (int c = tid; c < 2048; c += 512) {            // sA: 256 rows x 64 e
        int row = c >> 3, c8 = c & 7;
        *(bf16x8*)(sA + row * SA_STR + c8 * 8) =
            *(const bf16x8*)(ctxdm + ((size_t)(b * NS + row)) * DIMD + j * 64 + c8 * 8);
    }
    for (int c = tid; c < 2048; c += 512) {            // sCT: 64 cols x 256 s
        int col = c >> 5, s8 = c & 31;
        *(bf16x8*)(sCT + col * SCT_STR + s8 * 8) =
            *(const bf16x8*)(ctxT + ((size_t)(b * DIMD) + j * 64 + col) * NS + s8 * 8);
    }
    for (int c = tid; c < NT * 64; c += 512) {         // sQ
        int tt = c >> 6, e = c & 63;
        sQ[c] = qmf[((size_t)tt * NB + b) * DIMD + j * 64 + e];
    }
    sqh4[(tid >> 7) * SR_STR + (tid & 127)] = qh[(size_t)b * DIMD + tid];
    // weight slice -> registers: thread (m,cl,q) owns d in [q*128,(q+1)*128)
    int m = tid >> 8, cl = (tid >> 2) & 63, q = tid & 3;
    const __bf16* wp = (m ? wrrT : wrmT) + ((size_t)(j * 64 + cl)) * DIMD + q * 128;
    bf16x8 wreg[16];
#pragma unroll
    for (int u = 0; u < 16; u++) wreg[u] = *(const bf16x8*)(wp + u * 8);

    float wm[8];
#pragma unroll
    for (int u = 0; u < 8; u++) wm[u] = wms[j * 64 + i * 8 + u];
    if (tid < 64) {
        srm[tid] = brm[j * 64 + tid];            // rm_0 slice (r0 = 0)
        sh[tid]  = tanh_fast(brr[j * 64 + tid]); // h_0 slice
    }
    __syncthreads();

    for (int t = 0; t < NT; t++) {
        unsigned tag = (unsigned)(t + 1);
        // ---- phase A: partial logits, published directly from the loop ----
        float rq[8];
#pragma unroll
        for (int u = 0; u < 8; u++) rq[u] = srm[i * 8 + u] + sQ[t * 64 + i * 8 + u];
#pragma unroll
        for (int k = 0; k < 4; k++) {
            int s = wave * 32 + k * 8 + g;
            bf16x8 cv = *(const bf16x8*)(sA + s * SA_STR + i * 8);
            float a = 0.f;
#pragma unroll
            for (int u = 0; u < 8; u++)
                a += tanh_fast((float)cv[u] + rq[u]) * wm[u];
            a += __shfl_xor(a, 1); a += __shfl_xor(a, 2); a += __shfl_xor(a, 4);
            if (i == 0) pub64(&parts[(b * 8 + j) * NS + s], a, tag);
        }

        // ---- phase B1: batched poll, softmax, weighted ctx sum -> r-slice ----
        {
            int s = tid >> 1, jh = (tid & 1) * 4;
            const u64* p0 = &parts[(b * 8 + jh + 0) * NS + s];
            const u64* p1 = &parts[(b * 8 + jh + 1) * NS + s];
            const u64* p2 = &parts[(b * 8 + jh + 2) * NS + s];
            const u64* p3 = &parts[(b * 8 + jh + 3) * NS + s];
            u64 v0, v1, v2, v3;
            for (;;) {
                v0 = __hip_atomic_load(p0, __ATOMIC_RELAXED, __HIP_MEMORY_SCOPE_AGENT);
                v1 = __hip_atomic_load(p1, __ATOMIC_RELAXED, __HIP_MEMORY_SCOPE_AGENT);
                v2 = __hip_atomic_load(p2, __ATOMIC_RELAXED, __HIP_MEMORY_SCOPE_AGENT);
                v3 = __hip_atomic_load(p3, __ATOMIC_RELAXED, __HIP_MEMORY_SCOPE_AGENT);
                if ((unsigned)v0 == tag && (unsigned)v1 == tag &&
                    (unsigned)v2 == tag && (unsigned)v3 == tag) break;
                __builtin_amdgcn_s_sleep(1);
            }
            sq[tid] = __uint_as_float((unsigned)(v0 >> 32)) + __uint_as_float((unsigned)(v1 >> 32))
                    + __uint_as_float((unsigned)(v2 >> 32)) + __uint_as_float((unsigned)(v3 >> 32));
        }
        __syncthreads();
        float ev = 0.f;
        if (tid < NS) { ev = __expf(sq[2 * tid] + sq[2 * tid + 1]); sp[tid] = ev; }
#pragma unroll
        for (int off = 32; off; off >>= 1) ev += __shfl_xor(ev, off);
        if (tid < NS && lane == 0) s4[wave] = ev;
        __syncthreads();
        float inv = 1.f / (s4[0] + s4[1] + s4[2] + s4[3]);
        {
            const __bf16* cp = sCT + lane * SCT_STR + wave * 32;
            const float* pp = sp + wave * 32;
            float a = 0.f;
#pragma unroll
            for (int k = 0; k < 32; k += 8) {
                bf16x8 v = *(const bf16x8*)(cp + k);
#pragma unroll
                for (int u = 0; u < 8; u++) a = fmaf(pp[k + u], (float)v[u], a);
            }
            sps[wave * 68 + lane] = a;
        }
        __syncthreads();
        if (tid < 64) {
            float a = 0.f;
#pragma unroll
            for (int w2 = 0; w2 < 8; w2++) a += sps[w2 * 68 + tid];
            float rv = a * inv + sh[tid];
            pub64(&rpub[b * DIMD + j * 64 + tid], rv, tag);
        }

        // ---- phase B2 / final: gather full r ----
        sr4[(tid >> 7) * SR_STR + (tid & 127)] = poll64(&rpub[b * DIMD + tid], tag);
        __syncthreads();
        if (t < NT - 1) {
            // register-weight matvec -> rm/h (block-local)
            const float* sv = sr4 + q * SR_STR;   // q-groups on distinct banks
            float a0 = 0.f, a1 = 0.f;
#pragma unroll
            for (int u = 0; u < 16; u += 2) {
                bf16x8 w0 = wreg[u], w1 = wreg[u + 1];
#pragma unroll
                for (int e = 0; e < 8; e++) {
                    a0 = fmaf(sv[u * 8 + e],     (float)w0[e], a0);
                    a1 = fmaf(sv[u * 8 + 8 + e], (float)w1[e], a1);
                }
            }
            smv[tid] = a0 + a1;
            __syncthreads();
            if (tid < 128) {
                int m2 = tid >> 6, cl3 = tid & 63;
                float a = smv[m2 * 256 + cl3 * 4] + smv[m2 * 256 + cl3 * 4 + 1]
                        + smv[m2 * 256 + cl3 * 4 + 2] + smv[m2 * 256 + cl3 * 4 + 3];
                int col = j * 64 + cl3;
                if (m2 == 0) srm[cl3] = a + brm[col];
                else         sh[cl3]  = tanh_fast(a + brr[col]);
            }
            __syncthreads();
        } else {
            // fused k_final: g[j-slice] = r@W_rg + qh@W_qg + brg + bqg
            const __bf16* wp2 = (m ? wqgT : wrgT) + ((size_t)(j * 64 + cl)) * DIMD + q * 128;
            const float* sv = (m ? sqh4 : sr4) + q * SR_STR;
            float a0 = 0.f, a1 = 0.f;
#pragma unroll
            for (int u = 0; u < 16; u += 2) {
                bf16x8 w0 = *(const bf16x8*)(wp2 + u * 8);
                bf16x8 w1 = *(const bf16x8*)(wp2 + u * 8 + 8);
#pragma unroll
                for (int e = 0; e < 8; e++) {
                    a0 = fmaf(sv[u * 8 + e],     (float)w0[e], a0);
                    a1 = fmaf(sv[u * 8 + 8 + e], (float)w1[e], a1);
                }
            }
            smv[tid] = a0 + a1;
            __syncthreads();
            if (tid < 64) {
                int col = j * 64 + tid;
                float a = brg[col] + bqg[col];
#pragma unroll
                for (int m2 = 0; m2 < 2; m2++)
#pragma unroll
                    for (int q2 = 0; q2 < 4; q2++)
                        a += smv[m2 * 256 + tid * 4 + q2];
                out[(size_t)b * DIMD + col] = a;
            }
        }
    }
}

// ---------------- host ----------------

extern "C" void kernel_launch(void* const* d_in, const int* in_sizes, int n_in,
                              void* d_out, int out_size, void* d_ws, size_t ws_size,
                              hipStream_t stream) {
    const float* ctx_in = (const float*)d_in[0];
    const float* q_in   = (const float*)d_in[1];
    const float* qh     = (const float*)d_in[2];
    const float* img    = (const float*)d_in[3];
    const float* W_fc1  = (const float*)d_in[4];
    const float* b_fc1  = (const float*)d_in[5];
    const float* W_fc2  = (const float*)d_in[6];
    const float* b_fc2  = (const float*)d_in[7];
    const float* W_dm   = (const float*)d_in[8];
    const float* b_dm   = (const float*)d_in[9];
    const float* W_rm   = (const float*)d_in[10];
    const float* b_rm   = (const float*)d_in[11];
    const float* W_qm   = (const float*)d_in[12];
    const float* b_qm   = (const float*)d_in[13];
    const float* W_rr   = (const float*)d_in[14];
    const float* b_rr   = (const float*)d_in[15];
    const float* W_rg   = (const float*)d_in[16];
    const float* b_rg   = (const float*)d_in[17];
    const float* W_qg   = (const float*)d_in[18];
    const float* b_qg   = (const float*)d_in[19];
    const float* W_ms   = (const float*)d_in[20];
    // d_in[21] = b_ms: unused (softmax shift-invariant)

    // workspace layout. RULE: x-region aliases acat -> only WRITTEN after g1
    // consumed acat (round-8 NaN was a violation).
    char* w = (char*)d_ws;
    __bf16* acat  = (__bf16*)w;  w += (size_t)8192 * 1024 * 2;   // 16.78 MB, dead after g1
    __bf16* qp    = (__bf16*)w;  w += (size_t)1024 * 512 * 2;
    __bf16* wcatT = (__bf16*)w;  w += (size_t)512 * 1024 * 2;
    __bf16* wdmT  = (__bf16*)w;  w += (size_t)512 * 512 * 2;
    __bf16* wqmT  = (__bf16*)w;  w += (size_t)512 * 512 * 2;
    __bf16* wrmT  = (__bf16*)w;  w += (size_t)512 * 512 * 2;
    __bf16* wrrT  = (__bf16*)w;  w += (size_t)512 * 512 * 2;
    __bf16* wrgT  = (__bf16*)w;  w += (size_t)512 * 512 * 2;
    __bf16* wqgT  = (__bf16*)w;  w += (size_t)512 * 512 * 2;
    __bf16* ctxb  = (__bf16*)w;  w += (size_t)8192 * 512 * 2;
    __bf16* ctxdm = (__bf16*)w;  w += (size_t)8192 * 512 * 2;
    // sub-allocate dead acat region (written only after g1 consumed it)
    char* x = (char*)acat;
    __bf16* ctxT  = (__bf16*)x;  x += (size_t)NB * DIMD * NS * 2;  // 8.39 MB
    float*  qmf   = (float*)x;   x += (size_t)1024 * 512 * 4;      // 2.10 MB
    u64*    rpub  = (u64*)x;     x += (size_t)NB * DIMD * 8;       // 128 KB tagged
    u64*    parts = (u64*)x;     x += (size_t)NB * 8 * NS * 8;     // 512 KB tagged

    // 1. fused prep: acat + qp + all eight weight transposes
    k_prep_all<<<12288, 256, 0, stream>>>(ctx_in, img, q_in, W_fc1, W_fc2, W_dm,
                                          W_qm, W_rm, W_rr, W_rg, W_qg, acat, qp,
                                          wcatT, wdmT, wqmT, wrmT, wrrT, wrgT, wqgT);
    // 2. g1: ctx = acat @ W_cat^T + bfc1 + bfc2  (128x64 tiles, 512 blocks = 2/CU)
    k_gemm<<<dim3(64, 8), 256, 0, stream>>>(acat, wcatT, b_fc1, b_fc2, ctxb, 8192, 512, 1024, 0);
    // 3. fused post-g1: g2 + qm GEMMs (128x64 tiles) + ctxT transpose (acat dead)
    k_fused<<<4672, 256, 0, stream>>>(ctxb, wdmT, b_dm, ctxdm, qp, wqmT, b_qm, qmf, ctxT);
    // 4. scan + fused final: 256 blocks (8 per batch) x 512 threads, tagged sync
    k_scan<<<256, 512, 0, stream>>>(ctxdm, ctxT, wrmT, wrrT, qmf, W_ms,
                                    b_rm, b_rr, qh, wrgT, wqgT, b_rg, b_qg,
                                    parts, rpub, (float*)d_out);
}